// Round 11
// baseline (211.428 us; speedup 1.0000x reference)
//
#include <hip/hip_runtime.h>

#define NPTS 768
#define CCH  128
#define NM4  36    // 35 deg<=4 monomials in (d,u,v) + 1 pad
#define NM2  10    // deg<=2 monomials
#define NCHUNK 4   // n-chunks (192 n's each)
#define CTILE (NPTS/NCHUNK)   // 192 n per chunk
#define NT   (CTILE/32)       // 6 MFMA tiles per chunk
#define PAIR (NPTS*CCH)
#define NACC 384   // apart accumulator size (3 x 128)
#define FINB 96    // k_fin grid
#define LOG2E 1.4426950408889634f

typedef __attribute__((ext_vector_type(8))) short bf16x8;   // 8 bf16 in 4 VGPRs
typedef __attribute__((ext_vector_type(16))) float f32x16;  // MFMA 32x32 acc
union Frag { unsigned int u[4]; bf16x8 h; };

__device__ __forceinline__ float fast_exp2(float x) {
  return __builtin_amdgcn_exp2f(x);   // v_exp_f32 (base-2)
}

// Truncation-based 3-way bf16 split: x = h0 + h1 + h2 + eps, |eps| <= 2^-27 |x|.
__device__ __forceinline__ void split3(float x, unsigned int& h0,
                                       unsigned int& h1, unsigned int& h2) {
  const unsigned int b0 = __float_as_uint(x);
  h0 = b0 >> 16;
  const float r1 = x - __uint_as_float(b0 & 0xFFFF0000u);
  const unsigned int b1 = __float_as_uint(r1);
  h1 = b1 >> 16;
  const float r2 = r1 - __uint_as_float(b1 & 0xFFFF0000u);
  h2 = __float_as_uint(r2) >> 16;
}

// ---- monomial index helpers ------------------------------------------------
// (a,b,c) = (deg d, deg u, deg v), a outermost. Constexpr for the fold.
__device__ constexpr int ct4i(int a, int b, int c) {
  int t = 0;
  for (int aa = 0; aa < a; ++aa) t += (5 - aa) * (6 - aa) / 2;
  for (int bb = 0; bb < b; ++bb) t += (5 - a - bb);
  return t + c;
}
__device__ __forceinline__ int t2i(int a, int b, int c) {
  int t = 0;
  for (int aa = 0; aa < a; ++aa) t += (3 - aa) * (4 - aa) / 2;
  for (int bb = 0; bb < b; ++bb) t += (3 - a - bb);
  return t + c;
}
// (i,j) = (deg d, deg v) for the 15-term u-folded basis, i-major (t15 = pad)
__device__ constexpr int tdi(int t) { return t<5?0 : t<9?1 : t<12?2 : t<14?3 : 4; }
__device__ constexpr int tdj(int t) { return t<5?t : t<9?t-5 : t<12?t-9 : t<14?t-12 : 0; }

// Compile-time u-fold of one basis monomial t: s = sum_b coef[t4i(i,b,j)] u^b.
template<int T>
__device__ __forceinline__ void fold_one(const float* __restrict__ A3,
                                         const float* __restrict__ B3, int c,
                                         float u1, float u2, float u3, float u4,
                                         float& sa, float& sb) {
  if constexpr (T >= 15) { sa = 0.f; sb = 0.f; }
  else {
    constexpr int I = tdi(T), J = tdj(T);
    sa = A3[ct4i(I,0,J)*CCH + c];
    sb = B3[ct4i(I,0,J)*CCH + c];
    if constexpr (I+J+1 <= 4) { sa = fmaf(A3[ct4i(I,1,J)*CCH+c], u1, sa);
                                sb = fmaf(B3[ct4i(I,1,J)*CCH+c], u1, sb); }
    if constexpr (I+J+2 <= 4) { sa = fmaf(A3[ct4i(I,2,J)*CCH+c], u2, sa);
                                sb = fmaf(B3[ct4i(I,2,J)*CCH+c], u2, sb); }
    if constexpr (I+J+3 <= 4) { sa = fmaf(A3[ct4i(I,3,J)*CCH+c], u3, sa);
                                sb = fmaf(B3[ct4i(I,3,J)*CCH+c], u3, sb); }
    if constexpr (I+J+4 <= 4) { sa = fmaf(A3[ct4i(I,4,J)*CCH+c], u4, sa);
                                sb = fmaf(B3[ct4i(I,4,J)*CCH+c], u4, sb); }
  }
}

// One packed MFMA B-word (k=TLO lo16, k=THI hi16) x 3 splits x {A,B polys}.
template<int TLO, int THI>
__device__ __forceinline__ void fold_word(const float* __restrict__ A3,
                                          const float* __restrict__ B3, int c,
                                          float u1, float u2, float u3, float u4,
                                          unsigned int& wa0, unsigned int& wa1,
                                          unsigned int& wa2, unsigned int& wb0,
                                          unsigned int& wb1, unsigned int& wb2) {
  float salo, sblo, sahi, sbhi;
  fold_one<TLO>(A3, B3, c, u1, u2, u3, u4, salo, sblo);
  fold_one<THI>(A3, B3, c, u1, u2, u3, u4, sahi, sbhi);
  salo *= LOG2E; sahi *= LOG2E;             // log2e folded into A-poly
  unsigned int a0,a1,a2, c0,c1,c2, b0,b1,b2, d0,d1,d2;
  split3(salo, a0, a1, a2); split3(sahi, c0, c1, c2);
  split3(sblo, b0, b1, b2); split3(sbhi, d0, d1, d2);
  wa0 = a0 | (c0 << 16); wa1 = a1 | (c1 << 16); wa2 = a2 | (c2 << 16);
  wb0 = b0 | (d0 << 16); wb1 = b1 | (d1 << 16); wb2 = b2 | (d2 << 16);
}

// ---------------------------------------------------------------------------
// k_fold12 — layer-1/2 fold (unchanged).
// ---------------------------------------------------------------------------
__global__ __launch_bounds__(128) void k_fold12(
    const float* __restrict__ x,
    const float* __restrict__ Wa1, const float* __restrict__ ba1,
    const float* __restrict__ Wb1, const float* __restrict__ bb1,
    const float* __restrict__ Wa2, const float* __restrict__ ba2,
    const float* __restrict__ Wb2, const float* __restrict__ bb2,
    float* __restrict__ norms, float* __restrict__ C2m,
    float* __restrict__ apart, unsigned int* __restrict__ ticket) {
  __shared__ float sA[128][NM2];
  __shared__ float sB[128][NM2];
  const int c = blockIdx.x;
  const int k = threadIdx.x;

  if (c < 6) {
    const int i = c*128 + k;
    const float p0 = x[3*i], p1 = x[3*i+1], p2 = x[3*i+2];
    norms[i] = sqrtf(p0*p0 + p1*p1 + p2*p2);
  }
  if (c == 6) {
    apart[k] = 0.f; apart[CCH + k] = 0.f; apart[2*CCH + k] = 0.f;
    if (k == 0) *ticket = 0u;
  }

  {
    const float A0 = Wa1[3*k], A1 = Wa1[3*k+1], A2c = Wa1[3*k+2], A3 = ba1[k];
    const float B0 = Wb1[3*k], B1 = Wb1[3*k+1], B2c = Wb1[3*k+2], B3 = bb1[k];
    const float g0 = A3*B3;              // 1
    const float g1 = A2c*B3 + A3*B2c;    // v
    const float g2 = A2c*B2c;            // v^2
    const float g3 = A1*B3 + A3*B1;      // u
    const float g4 = A1*B2c + A2c*B1;    // u v
    const float g5 = A1*B1;              // u^2
    const float g6 = A0*B3 + A3*B0;      // d
    const float g7 = A0*B2c + A2c*B0;    // d v
    const float g8 = A0*B1 + A1*B0;      // d u
    const float g9 = A0*B0;              // d^2
    const float wa = Wa2[c*CCH + k];
    const float wb = Wb2[c*CCH + k];
    sA[k][0] = wa*g0; sB[k][0] = wb*g0;
    sA[k][1] = wa*g1; sB[k][1] = wb*g1;
    sA[k][2] = wa*g2; sB[k][2] = wb*g2;
    sA[k][3] = wa*g3; sB[k][3] = wb*g3;
    sA[k][4] = wa*g4; sB[k][4] = wb*g4;
    sA[k][5] = wa*g5; sB[k][5] = wb*g5;
    sA[k][6] = wa*g6; sB[k][6] = wb*g6;
    sA[k][7] = wa*g7; sB[k][7] = wb*g7;
    sA[k][8] = wa*g8; sB[k][8] = wb*g8;
    sA[k][9] = wa*g9; sB[k][9] = wb*g9;
  }
  __syncthreads();

  for (int s = 64; s >= 1; s >>= 1) {
    if (k < s) {
      for (int t = 0; t < NM2; ++t) {
        sA[k][t] += sA[k+s][t];
        sB[k][t] += sB[k+s][t];
      }
    }
    __syncthreads();
  }
  if (k == 0) {
    sA[0][0] += ba2[c];
    sB[0][0] += bb2[c];
  }
  __syncthreads();

  if (k < 35) {
    int rem = k, a = 0;
    while (rem >= (5 - a)*(6 - a)/2) { rem -= (5 - a)*(6 - a)/2; ++a; }
    int b = 0;
    while (rem >= 5 - a - b) { rem -= 5 - a - b; ++b; }
    const int cc = rem;
    float s = 0.f;
    const int deg = a + b + cc;
    for (int a1 = 0; a1 <= a && a1 <= 2; ++a1)
      for (int b1 = 0; b1 <= b && b1 <= 2; ++b1)
        for (int c1 = 0; c1 <= cc && c1 <= 2; ++c1) {
          const int d1 = a1 + b1 + c1;
          if (d1 <= 2 && (deg - d1) <= 2)
            s += sA[0][t2i(a1, b1, c1)]
               * sB[0][t2i(a - a1, b - b1, cc - c1)];
        }
    C2m[c*NM4 + k] = s;
  }
  if (k == 35) C2m[c*NM4 + 35] = 0.f;
}

// ---------------------------------------------------------------------------
// k_pre2 (128 blocks x 64 thr): A3mT/B3mT = layer-3 fold, transposed (36x128).
// ---------------------------------------------------------------------------
__global__ void k_pre2(const float* __restrict__ Wa3, const float* __restrict__ ba3,
                       const float* __restrict__ Wb3, const float* __restrict__ bb3,
                       const float* __restrict__ C2m,
                       float* __restrict__ A3mT, float* __restrict__ B3mT) {
  const int c = blockIdx.x;
  const int j = threadIdx.x;
  if (j >= NM4) return;
  float sa = 0.f, sb = 0.f;
  if (j < 35) {
    for (int k = 0; k < CCH; ++k) {
      const float v = C2m[k*NM4 + j];
      sa += Wa3[c*CCH + k] * v;
      sb += Wb3[c*CCH + k] * v;
    }
    if (j == 0) { sa += ba3[c]; sb += bb3[c]; }
  }
  A3mT[j*CCH + c] = sa;
  B3mT[j*CCH + c] = sb;
}

// 12 MFMAs of one tile; first of each chain consumes the hoisted zero Z
// (no per-tile acc re-zero — saves 32 v_mov/tile).
#define MFMA12Z(AA0, AA1, AA2)                                                 \
  do {                                                                         \
    accA = __builtin_amdgcn_mfma_f32_32x32x16_bf16((AA2).h, ba0.h, Z,    0,0,0);\
    accA = __builtin_amdgcn_mfma_f32_32x32x16_bf16((AA1).h, ba1.h, accA, 0,0,0);\
    accA = __builtin_amdgcn_mfma_f32_32x32x16_bf16((AA0).h, ba2.h, accA, 0,0,0);\
    accA = __builtin_amdgcn_mfma_f32_32x32x16_bf16((AA1).h, ba0.h, accA, 0,0,0);\
    accA = __builtin_amdgcn_mfma_f32_32x32x16_bf16((AA0).h, ba1.h, accA, 0,0,0);\
    accA = __builtin_amdgcn_mfma_f32_32x32x16_bf16((AA0).h, ba0.h, accA, 0,0,0);\
    accB = __builtin_amdgcn_mfma_f32_32x32x16_bf16((AA2).h, bb0.h, Z,    0,0,0);\
    accB = __builtin_amdgcn_mfma_f32_32x32x16_bf16((AA1).h, bb1.h, accB, 0,0,0);\
    accB = __builtin_amdgcn_mfma_f32_32x32x16_bf16((AA0).h, bb2.h, accB, 0,0,0);\
    accB = __builtin_amdgcn_mfma_f32_32x32x16_bf16((AA1).h, bb0.h, accB, 0,0,0);\
    accB = __builtin_amdgcn_mfma_f32_32x32x16_bf16((AA0).h, bb1.h, accB, 0,0,0);\
    accB = __builtin_amdgcn_mfma_f32_32x32x16_bf16((AA0).h, bb0.h, accB, 0,0,0);\
  } while (0)

// Max tree over 16 floats (v_max3-friendly).
#define MAXTREE(F, OUT)                                                        \
  const float _x0 = fmaxf(fmaxf(F[0], F[1]), F[2]);                            \
  const float _x1 = fmaxf(fmaxf(F[3], F[4]), F[5]);                            \
  const float _x2 = fmaxf(fmaxf(F[6], F[7]), F[8]);                            \
  const float _x3 = fmaxf(fmaxf(F[9], F[10]), F[11]);                          \
  const float _x4 = fmaxf(fmaxf(F[12], F[13]), F[14]);                         \
  const float OUT = fmaxf(fmaxf(fmaxf(_x0, _x1), _x2),                         \
                          fmaxf(fmaxf(_x3, _x4), F[15]));

// PV over one tile; E_EXPR(r) gives the exp2 argument for slot r.
#define PVBLK(TB, E_EXPR)                                                      \
  _Pragma("unroll")                                                            \
  for (int rg = 0; rg < 4; ++rg) {                                             \
    _Pragma("unroll")                                                          \
    for (int q = 0; q < 4; ++q) {                                              \
      const int r = rg*4 + q;                                                  \
      const float e = fast_exp2(E_EXPR);                                       \
      const float4 xv = xt[(TB) + rg*8 + hl*4 + q];                            \
      srun += e;                                                               \
      a0r = fmaf(e, xv.x, a0r);                                                \
      a1r = fmaf(e, xv.y, a1r);                                                \
      a2r = fmaf(e, xv.z, a2r);                                                \
    }                                                                          \
  }

// ---------------------------------------------------------------------------
// k_main (v11 = v9 + __launch_bounds__(256, 6)): grid (768, 4), 256 thr = 4
// waves; block owns one m, wave owns one 32-col c-tile. Byte-for-byte v9
// arithmetic (R10's BFT hoist regressed — reverted).
// R9 counters: occupancy 32% (~10 waves/CU) though static limits allow far
// more (VGPR 60 -> 8 waves/SIMD legal; LDS 21.5 KB -> 7 blocks/CU). The
// binding limit was the DECLARED bounds(256,4) = 4 blocks/CU target. (256,6)
// raises the cap to 6 blocks/CU; VGPR budget at 6 waves/EU is ~85 and the
// body uses 60 — 25-reg headroom, no R3-style spill risk (R3's body NEEDED
// >84; this one doesn't).
// A layout: row=lane&31, k=(lane>>5)*8+e, word pairs lo/hi. C/D (verified):
// col=lane&31, row=(reg&3)+8*(reg>>2)+4*(lane>>5).
// ---------------------------------------------------------------------------
__global__ __launch_bounds__(256, 6) void k_main(
    const float* __restrict__ x, const float* __restrict__ norms,
    const float* __restrict__ A3mT, const float* __restrict__ B3mT,
    float* __restrict__ Mp, float* __restrict__ Sp,
    float* __restrict__ A0p, float* __restrict__ A1p, float* __restrict__ A2p) {
  __shared__ __align__(16) float4 xt[CTILE];       // (x0,x1,x2,|x_n|), 3 KB
  __shared__ __align__(16) uint4 af[NT][3][64];    // A-frags: tile x split x lane, 18 KB
  const int tid = threadIdx.x;
  const int wid = tid >> 6;          // c-tile index 0..3
  const int lane = tid & 63;
  const int hl = lane >> 5;          // k-slice half
  const int ln = lane & 31;          // A row / B,C col
  const int m = blockIdx.x;
  const int chunk = blockIdx.y;
  const int c = wid*32 + ln;         // this lane's channel column

  // Stage this chunk's 192 n's (x, |x|) into LDS.
  for (int p = tid; p < CTILE; p += 256) {
    const int n = chunk*CTILE + p;
    xt[p] = make_float4(x[3*n], x[3*n+1], x[3*n+2], norms[n]);
  }

  const float u = norms[m];
  const float xm0 = x[3*m], xm1 = x[3*m+1], xm2 = x[3*m+2];
  const float uu = u*u;
  const float u1 = u, u2 = uu, u3 = uu*u, u4 = uu*uu;

  // ---- B-fragments: compile-time u-fold + split3 + MFMA-pack -------------
  Frag ba0, ba1, ba2, bb0, bb1, bb2;
  if (hl == 0) {
    fold_word<0,1>(A3mT, B3mT, c, u1,u2,u3,u4, ba0.u[0],ba1.u[0],ba2.u[0], bb0.u[0],bb1.u[0],bb2.u[0]);
    fold_word<2,3>(A3mT, B3mT, c, u1,u2,u3,u4, ba0.u[1],ba1.u[1],ba2.u[1], bb0.u[1],bb1.u[1],bb2.u[1]);
    fold_word<4,5>(A3mT, B3mT, c, u1,u2,u3,u4, ba0.u[2],ba1.u[2],ba2.u[2], bb0.u[2],bb1.u[2],bb2.u[2]);
    fold_word<6,7>(A3mT, B3mT, c, u1,u2,u3,u4, ba0.u[3],ba1.u[3],ba2.u[3], bb0.u[3],bb1.u[3],bb2.u[3]);
  } else {
    fold_word<8,9>  (A3mT, B3mT, c, u1,u2,u3,u4, ba0.u[0],ba1.u[0],ba2.u[0], bb0.u[0],bb1.u[0],bb2.u[0]);
    fold_word<10,11>(A3mT, B3mT, c, u1,u2,u3,u4, ba0.u[1],ba1.u[1],ba2.u[1], bb0.u[1],bb1.u[1],bb2.u[1]);
    fold_word<12,13>(A3mT, B3mT, c, u1,u2,u3,u4, ba0.u[2],ba1.u[2],ba2.u[2], bb0.u[2],bb1.u[2],bb2.u[2]);
    fold_word<14,15>(A3mT, B3mT, c, u1,u2,u3,u4, ba0.u[3],ba1.u[3],ba2.u[3], bb0.u[3],bb1.u[3],bb2.u[3]);
  }

  __syncthreads();   // xt staged

  // ---- Build phase: this wave builds A-frags for tiles wid, wid+4 --------
  for (int t = wid; t < NT; t += 4) {
    const float4 xn = xt[t*32 + ln];
    const float v = xn.w;
    const float dot = xm0*xn.x + xm1*xn.y + xm2*xn.z;
    const float d2 = uu + v*v - 2.f*dot;
    const float d = (d2 > 0.f) ? sqrtf(d2) : 0.f;   // grad-safe cdist semantics
    const float v2 = v*v, v3 = v2*v, v4 = v2*v2;
    const float dd = d*d, d3 = dd*d, d4 = dd*dd;
    float mono[8];
    if (hl == 0) {
      mono[0] = 1.f;   mono[1] = v;     mono[2] = v2;    mono[3] = v3;
      mono[4] = v4;    mono[5] = d;     mono[6] = d*v;   mono[7] = d*v2;
    } else {
      mono[0] = d*v3;  mono[1] = dd;    mono[2] = dd*v;  mono[3] = dd*v2;
      mono[4] = d3;    mono[5] = d3*v;  mono[6] = d4;    mono[7] = 0.f;
    }
    Frag A0f, A1f, A2f;
    #pragma unroll
    for (int p = 0; p < 4; ++p) {
      unsigned int l0, l1, l2, g0, g1, g2;
      split3(mono[2*p],   l0, l1, l2);
      split3(mono[2*p+1], g0, g1, g2);
      A0f.u[p] = l0 | (g0 << 16);
      A1f.u[p] = l1 | (g1 << 16);
      A2f.u[p] = l2 | (g2 << 16);
    }
    af[t][0][lane] = *(const uint4*)A0f.u;
    af[t][1][lane] = *(const uint4*)A1f.u;
    af[t][2][lane] = *(const uint4*)A2f.u;
  }

  __syncthreads();   // A-frags built

  float mrun, srun = 0.f, a0r = 0.f, a1r = 0.f, a2r = 0.f;

  f32x16 Z;
  #pragma unroll
  for (int r = 0; r < 16; ++r) Z[r] = 0.f;

  // ---- Pipeline prologue: tile 0's MFMAs in flight before the loop ----
  Frag A0f, A1f, A2f;
  *(uint4*)A0f.u = af[0][0][lane];
  *(uint4*)A1f.u = af[0][1][lane];
  *(uint4*)A2f.u = af[0][2][lane];
  f32x16 accA, accB;
  MFMA12Z(A0f, A1f, A2f);

  // ---- Tile 0 (peeled: no prior max) ----
  {
    *(uint4*)A0f.u = af[1][0][lane];
    *(uint4*)A1f.u = af[1][1][lane];
    *(uint4*)A2f.u = af[1][2][lane];
    float f[16];
    #pragma unroll
    for (int r = 0; r < 16; ++r) f[r] = accA[r]*accB[r];   // logits * log2e
    MFMA12Z(A0f, A1f, A2f);                                 // tile 1 in flight
    MAXTREE(f, hx0);
    mrun = hx0;
    PVBLK(0, f[r] - hx0);
  }

  for (int tile = 1; tile < NT; ++tile) {
    // Prefetch next tile's A-frags (issue only; consumed after f extract).
    if (tile + 1 < NT) {
      *(uint4*)A0f.u = af[tile+1][0][lane];
      *(uint4*)A1f.u = af[tile+1][1][lane];
      *(uint4*)A2f.u = af[tile+1][2][lane];
    }

    // Drain this tile's accumulators (waits on the in-flight MFMA chain);
    // -mrun folded into the drain fma.
    float f[16];
    #pragma unroll
    for (int r = 0; r < 16; ++r) f[r] = fmaf(accA[r], accB[r], -mrun);

    // Issue next tile's MFMAs now — they execute under this tile's softmax.
    if (tile + 1 < NT) MFMA12Z(A0f, A1f, A2f);

    // Branch-free online update: fxp = max growth (0 when max unchanged —
    // then sc = exp2(0) = 1 and the rescale is a no-op, exactly as R7).
    MAXTREE(f, fx);
    const float fxp = fmaxf(fx, 0.f);
    const float sc = fast_exp2(-fxp);
    mrun += fxp;
    srun *= sc; a0r *= sc; a1r *= sc; a2r *= sc;
    PVBLK(tile*32, f[r] - fxp);
  }

  // Merge the two lane-halves' online states (each covered half the rows).
  {
    const float om = __shfl_xor(mrun, 32);
    const float os = __shfl_xor(srun, 32);
    const float o0 = __shfl_xor(a0r, 32);
    const float o1 = __shfl_xor(a1r, 32);
    const float o2 = __shfl_xor(a2r, 32);
    const float M  = fmaxf(mrun, om);
    const float e1 = fast_exp2(mrun - M);
    const float e2 = fast_exp2(om - M);
    if (hl == 0) {
      const int idx = chunk*PAIR + m*CCH + c;
      Mp[idx]  = M;
      Sp[idx]  = fmaf(srun, e1, os*e2);
      A0p[idx] = fmaf(a0r, e1, o0*e2);
      A1p[idx] = fmaf(a1r, e1, o1*e2);
      A2p[idx] = fmaf(a2r, e1, o2*e2);
    }
  }
}

// ---------------------------------------------------------------------------
// k_fin (96 blocks x 256): merge NCHUNK=4 partials per (m,c), normalize,
// LDS-reduce 8 m-rows, atomics into apart; ticketed Wf contraction + out.
// ---------------------------------------------------------------------------
__global__ __launch_bounds__(256) void k_fin(
    const float* __restrict__ x,
    const float* __restrict__ Mp, const float* __restrict__ Sp,
    const float* __restrict__ A0p, const float* __restrict__ A1p,
    const float* __restrict__ A2p,
    const float* __restrict__ Wf,
    float* __restrict__ apart, unsigned int* __restrict__ ticket,
    float* __restrict__ out) {
  __shared__ float red2[2][3][CCH];
  __shared__ float red[CCH][6];
  __shared__ bool last;
  const int tid = threadIdx.x;
  const int ml = tid >> 7;
  const int c = tid & 127;

  float s0 = 0.f, s1 = 0.f, s2 = 0.f;
  #pragma unroll
  for (int j = 0; j < 4; ++j) {
    const int m = blockIdx.x*8 + ml*4 + j;
    const int gid = m*CCH + c;
    float mm[NCHUNK];
    #pragma unroll
    for (int p = 0; p < NCHUNK; ++p) mm[p] = Mp[p*PAIR + gid];
    float M = mm[0];
    #pragma unroll
    for (int p = 1; p < NCHUNK; ++p) M = fmaxf(M, mm[p]);
    float W = 0.f, g0 = 0.f, g1 = 0.f, g2 = 0.f;
    #pragma unroll
    for (int p = 0; p < NCHUNK; ++p) {
      const float ep = fast_exp2(mm[p] - M);
      W  = fmaf(Sp[p*PAIR+gid],  ep, W);
      g0 = fmaf(A0p[p*PAIR+gid], ep, g0);
      g1 = fmaf(A1p[p*PAIR+gid], ep, g1);
      g2 = fmaf(A2p[p*PAIR+gid], ep, g2);
    }
    const float inv = 1.f / W;
    s0 = fmaf(g0, inv, s0);
    s1 = fmaf(g1, inv, s1);
    s2 = fmaf(g2, inv, s2);
  }
  red2[ml][0][c] = s0; red2[ml][1][c] = s1; red2[ml][2][c] = s2;
  __syncthreads();
  for (int p = tid; p < NACC; p += 256) {
    const int i = p >> 7, cc = p & 127;
    atomicAdd(&apart[p], red2[0][i][cc] + red2[1][i][cc]);
  }
  __threadfence();
  __syncthreads();
  if (tid == 0) {
    const unsigned int old = atomicAdd(ticket, 1u);
    last = (old == FINB - 1);
  }
  __syncthreads();
  if (!last) return;
  __threadfence();

  if (tid < CCH) {
    const int cc = tid;
    const float a0 = __hip_atomic_load(&apart[cc],          __ATOMIC_RELAXED, __HIP_MEMORY_SCOPE_AGENT);
    const float a1 = __hip_atomic_load(&apart[CCH + cc],    __ATOMIC_RELAXED, __HIP_MEMORY_SCOPE_AGENT);
    const float a2 = __hip_atomic_load(&apart[2*CCH + cc],  __ATOMIC_RELAXED, __HIP_MEMORY_SCOPE_AGENT);
    const float w0 = Wf[cc], w1 = Wf[CCH + cc];
    red[cc][0] = w0*a0; red[cc][1] = w0*a1; red[cc][2] = w0*a2;
    red[cc][3] = w1*a0; red[cc][4] = w1*a1; red[cc][5] = w1*a2;
  }
  __syncthreads();
  if (tid < 6) {
    float s = 0.f;
    for (int k = 0; k < CCH; ++k) s += red[k][tid];
    out[3 + tid] = s;
  }
  if (tid < 3) out[tid] = x[tid];
}

// ---------------------------------------------------------------------------
extern "C" void kernel_launch(void* const* d_in, const int* in_sizes, int n_in,
                              void* d_out, int out_size, void* d_ws, size_t ws_size,
                              hipStream_t stream) {
  const float* x   = (const float*)d_in[0];
  const float* Wa1 = (const float*)d_in[1];
  const float* ba1 = (const float*)d_in[2];
  const float* Wb1 = (const float*)d_in[3];
  const float* bb1 = (const float*)d_in[4];
  const float* Wa2 = (const float*)d_in[5];
  const float* ba2 = (const float*)d_in[6];
  const float* Wb2 = (const float*)d_in[7];
  const float* bb2 = (const float*)d_in[8];
  const float* Wa3 = (const float*)d_in[9];
  const float* ba3 = (const float*)d_in[10];
  const float* Wb3 = (const float*)d_in[11];
  const float* bb3 = (const float*)d_in[12];
  const float* Wf  = (const float*)d_in[13];
  float* out = (float*)d_out;

  float* ws     = (float*)d_ws;
  float* norms  = ws;                      // 768
  float* C2m    = norms + NPTS;            // 128*36
  float* A3mT   = C2m   + CCH*NM4;         // 36*128
  float* B3mT   = A3mT  + NM4*CCH;         // 36*128
  float* Mp     = B3mT  + NM4*CCH;         // 4*98304
  float* Sp     = Mp    + NCHUNK*PAIR;
  float* A0p    = Sp    + NCHUNK*PAIR;
  float* A1p    = A0p   + NCHUNK*PAIR;
  float* A2p    = A1p   + NCHUNK*PAIR;
  float* apart  = A2p   + NCHUNK*PAIR;     // 384
  unsigned int* ticket = (unsigned int*)(apart + NACC);

  hipLaunchKernelGGL(k_fold12, dim3(CCH), dim3(128), 0, stream,
                     x, Wa1, ba1, Wb1, bb1, Wa2, ba2, Wb2, bb2,
                     norms, C2m, apart, ticket);
  hipLaunchKernelGGL(k_pre2, dim3(CCH), dim3(64), 0, stream,
                     Wa3, ba3, Wb3, bb3, C2m, A3mT, B3mT);
  hipLaunchKernelGGL(k_main, dim3(NPTS, NCHUNK), dim3(256), 0, stream,
                     x, norms, A3mT, B3mT, Mp, Sp, A0p, A1p, A2p);
  hipLaunchKernelGGL(k_fin, dim3(FINB), dim3(256), 0, stream,
                     x, Mp, Sp, A0p, A1p, A2p, Wf, apart, ticket, out);
}

// Round 12
// 147.604 us; speedup vs baseline: 1.4324x; 1.4324x over previous
//
#include <hip/hip_runtime.h>

#define NPTS 768
#define CCH  128
#define NM4  36    // 35 deg<=4 monomials in (d,u,v) + 1 pad
#define NM2  10    // deg<=2 monomials
#define NCHUNK 4   // n-chunks (192 n's each)
#define CTILE (NPTS/NCHUNK)   // 192 n per chunk
#define NT   (CTILE/32)       // 6 MFMA tiles per chunk
#define PAIR (NPTS*CCH)
#define NACC 384   // apart accumulator size (3 x 128)
#define FINB 96    // k_fin grid
#define LOG2E 1.4426950408889634f

typedef __attribute__((ext_vector_type(8))) short bf16x8;   // 8 bf16 in 4 VGPRs
typedef __attribute__((ext_vector_type(16))) float f32x16;  // MFMA 32x32 acc
union Frag { unsigned int u[4]; bf16x8 h; };

__device__ __forceinline__ float fast_exp2(float x) {
  return __builtin_amdgcn_exp2f(x);   // v_exp_f32 (base-2)
}

// Truncation-based 3-way bf16 split: x = h0 + h1 + h2 + eps, |eps| <= 2^-27 |x|.
__device__ __forceinline__ void split3(float x, unsigned int& h0,
                                       unsigned int& h1, unsigned int& h2) {
  const unsigned int b0 = __float_as_uint(x);
  h0 = b0 >> 16;
  const float r1 = x - __uint_as_float(b0 & 0xFFFF0000u);
  const unsigned int b1 = __float_as_uint(r1);
  h1 = b1 >> 16;
  const float r2 = r1 - __uint_as_float(b1 & 0xFFFF0000u);
  h2 = __float_as_uint(r2) >> 16;
}

// ---- monomial index helpers ------------------------------------------------
// (a,b,c) = (deg d, deg u, deg v), a outermost. Constexpr for the fold.
__device__ constexpr int ct4i(int a, int b, int c) {
  int t = 0;
  for (int aa = 0; aa < a; ++aa) t += (5 - aa) * (6 - aa) / 2;
  for (int bb = 0; bb < b; ++bb) t += (5 - a - bb);
  return t + c;
}
__device__ __forceinline__ int t2i(int a, int b, int c) {
  int t = 0;
  for (int aa = 0; aa < a; ++aa) t += (3 - aa) * (4 - aa) / 2;
  for (int bb = 0; bb < b; ++bb) t += (3 - a - bb);
  return t + c;
}
// (i,j) = (deg d, deg v) for the 15-term u-folded basis, i-major (t15 = pad)
__device__ constexpr int tdi(int t) { return t<5?0 : t<9?1 : t<12?2 : t<14?3 : 4; }
__device__ constexpr int tdj(int t) { return t<5?t : t<9?t-5 : t<12?t-9 : t<14?t-12 : 0; }

// Compile-time u-fold of one basis monomial t: s = sum_b coef[t4i(i,b,j)] u^b.
template<int T>
__device__ __forceinline__ void fold_one(const float* __restrict__ A3,
                                         const float* __restrict__ B3, int c,
                                         float u1, float u2, float u3, float u4,
                                         float& sa, float& sb) {
  if constexpr (T >= 15) { sa = 0.f; sb = 0.f; }
  else {
    constexpr int I = tdi(T), J = tdj(T);
    sa = A3[ct4i(I,0,J)*CCH + c];
    sb = B3[ct4i(I,0,J)*CCH + c];
    if constexpr (I+J+1 <= 4) { sa = fmaf(A3[ct4i(I,1,J)*CCH+c], u1, sa);
                                sb = fmaf(B3[ct4i(I,1,J)*CCH+c], u1, sb); }
    if constexpr (I+J+2 <= 4) { sa = fmaf(A3[ct4i(I,2,J)*CCH+c], u2, sa);
                                sb = fmaf(B3[ct4i(I,2,J)*CCH+c], u2, sb); }
    if constexpr (I+J+3 <= 4) { sa = fmaf(A3[ct4i(I,3,J)*CCH+c], u3, sa);
                                sb = fmaf(B3[ct4i(I,3,J)*CCH+c], u3, sb); }
    if constexpr (I+J+4 <= 4) { sa = fmaf(A3[ct4i(I,4,J)*CCH+c], u4, sa);
                                sb = fmaf(B3[ct4i(I,4,J)*CCH+c], u4, sb); }
  }
}

// One packed MFMA B-word (k=TLO lo16, k=THI hi16) x 3 splits x {A,B polys}.
template<int TLO, int THI>
__device__ __forceinline__ void fold_word(const float* __restrict__ A3,
                                          const float* __restrict__ B3, int c,
                                          float u1, float u2, float u3, float u4,
                                          unsigned int& wa0, unsigned int& wa1,
                                          unsigned int& wa2, unsigned int& wb0,
                                          unsigned int& wb1, unsigned int& wb2) {
  float salo, sblo, sahi, sbhi;
  fold_one<TLO>(A3, B3, c, u1, u2, u3, u4, salo, sblo);
  fold_one<THI>(A3, B3, c, u1, u2, u3, u4, sahi, sbhi);
  salo *= LOG2E; sahi *= LOG2E;             // log2e folded into A-poly
  unsigned int a0,a1,a2, c0,c1,c2, b0,b1,b2, d0,d1,d2;
  split3(salo, a0, a1, a2); split3(sahi, c0, c1, c2);
  split3(sblo, b0, b1, b2); split3(sbhi, d0, d1, d2);
  wa0 = a0 | (c0 << 16); wa1 = a1 | (c1 << 16); wa2 = a2 | (c2 << 16);
  wb0 = b0 | (d0 << 16); wb1 = b1 | (d1 << 16); wb2 = b2 | (d2 << 16);
}

// ---------------------------------------------------------------------------
// k_fold12 — layer-1/2 fold (unchanged).
// ---------------------------------------------------------------------------
__global__ __launch_bounds__(128) void k_fold12(
    const float* __restrict__ x,
    const float* __restrict__ Wa1, const float* __restrict__ ba1,
    const float* __restrict__ Wb1, const float* __restrict__ bb1,
    const float* __restrict__ Wa2, const float* __restrict__ ba2,
    const float* __restrict__ Wb2, const float* __restrict__ bb2,
    float* __restrict__ norms, float* __restrict__ C2m,
    float* __restrict__ apart, unsigned int* __restrict__ ticket) {
  __shared__ float sA[128][NM2];
  __shared__ float sB[128][NM2];
  const int c = blockIdx.x;
  const int k = threadIdx.x;

  if (c < 6) {
    const int i = c*128 + k;
    const float p0 = x[3*i], p1 = x[3*i+1], p2 = x[3*i+2];
    norms[i] = sqrtf(p0*p0 + p1*p1 + p2*p2);
  }
  if (c == 6) {
    apart[k] = 0.f; apart[CCH + k] = 0.f; apart[2*CCH + k] = 0.f;
    if (k == 0) *ticket = 0u;
  }

  {
    const float A0 = Wa1[3*k], A1 = Wa1[3*k+1], A2c = Wa1[3*k+2], A3 = ba1[k];
    const float B0 = Wb1[3*k], B1 = Wb1[3*k+1], B2c = Wb1[3*k+2], B3 = bb1[k];
    const float g0 = A3*B3;              // 1
    const float g1 = A2c*B3 + A3*B2c;    // v
    const float g2 = A2c*B2c;            // v^2
    const float g3 = A1*B3 + A3*B1;      // u
    const float g4 = A1*B2c + A2c*B1;    // u v
    const float g5 = A1*B1;              // u^2
    const float g6 = A0*B3 + A3*B0;      // d
    const float g7 = A0*B2c + A2c*B0;    // d v
    const float g8 = A0*B1 + A1*B0;      // d u
    const float g9 = A0*B0;              // d^2
    const float wa = Wa2[c*CCH + k];
    const float wb = Wb2[c*CCH + k];
    sA[k][0] = wa*g0; sB[k][0] = wb*g0;
    sA[k][1] = wa*g1; sB[k][1] = wb*g1;
    sA[k][2] = wa*g2; sB[k][2] = wb*g2;
    sA[k][3] = wa*g3; sB[k][3] = wb*g3;
    sA[k][4] = wa*g4; sB[k][4] = wb*g4;
    sA[k][5] = wa*g5; sB[k][5] = wb*g5;
    sA[k][6] = wa*g6; sB[k][6] = wb*g6;
    sA[k][7] = wa*g7; sB[k][7] = wb*g7;
    sA[k][8] = wa*g8; sB[k][8] = wb*g8;
    sA[k][9] = wa*g9; sB[k][9] = wb*g9;
  }
  __syncthreads();

  for (int s = 64; s >= 1; s >>= 1) {
    if (k < s) {
      for (int t = 0; t < NM2; ++t) {
        sA[k][t] += sA[k+s][t];
        sB[k][t] += sB[k+s][t];
      }
    }
    __syncthreads();
  }
  if (k == 0) {
    sA[0][0] += ba2[c];
    sB[0][0] += bb2[c];
  }
  __syncthreads();

  if (k < 35) {
    int rem = k, a = 0;
    while (rem >= (5 - a)*(6 - a)/2) { rem -= (5 - a)*(6 - a)/2; ++a; }
    int b = 0;
    while (rem >= 5 - a - b) { rem -= 5 - a - b; ++b; }
    const int cc = rem;
    float s = 0.f;
    const int deg = a + b + cc;
    for (int a1 = 0; a1 <= a && a1 <= 2; ++a1)
      for (int b1 = 0; b1 <= b && b1 <= 2; ++b1)
        for (int c1 = 0; c1 <= cc && c1 <= 2; ++c1) {
          const int d1 = a1 + b1 + c1;
          if (d1 <= 2 && (deg - d1) <= 2)
            s += sA[0][t2i(a1, b1, c1)]
               * sB[0][t2i(a - a1, b - b1, cc - c1)];
        }
    C2m[c*NM4 + k] = s;
  }
  if (k == 35) C2m[c*NM4 + 35] = 0.f;
}

// ---------------------------------------------------------------------------
// k_pre2 (128 blocks x 64 thr): A3mT/B3mT = layer-3 fold, transposed (36x128).
// ---------------------------------------------------------------------------
__global__ void k_pre2(const float* __restrict__ Wa3, const float* __restrict__ ba3,
                       const float* __restrict__ Wb3, const float* __restrict__ bb3,
                       const float* __restrict__ C2m,
                       float* __restrict__ A3mT, float* __restrict__ B3mT) {
  const int c = blockIdx.x;
  const int j = threadIdx.x;
  if (j >= NM4) return;
  float sa = 0.f, sb = 0.f;
  if (j < 35) {
    for (int k = 0; k < CCH; ++k) {
      const float v = C2m[k*NM4 + j];
      sa += Wa3[c*CCH + k] * v;
      sb += Wb3[c*CCH + k] * v;
    }
    if (j == 0) { sa += ba3[c]; sb += bb3[c]; }
  }
  A3mT[j*CCH + c] = sa;
  B3mT[j*CCH + c] = sb;
}

// 12 MFMAs of one tile; first of each chain consumes the hoisted zero Z
// (no per-tile acc re-zero — saves 32 v_mov/tile).
#define MFMA12Z(AA0, AA1, AA2)                                                 \
  do {                                                                         \
    accA = __builtin_amdgcn_mfma_f32_32x32x16_bf16((AA2).h, ba0.h, Z,    0,0,0);\
    accA = __builtin_amdgcn_mfma_f32_32x32x16_bf16((AA1).h, ba1.h, accA, 0,0,0);\
    accA = __builtin_amdgcn_mfma_f32_32x32x16_bf16((AA0).h, ba2.h, accA, 0,0,0);\
    accA = __builtin_amdgcn_mfma_f32_32x32x16_bf16((AA1).h, ba0.h, accA, 0,0,0);\
    accA = __builtin_amdgcn_mfma_f32_32x32x16_bf16((AA0).h, ba1.h, accA, 0,0,0);\
    accA = __builtin_amdgcn_mfma_f32_32x32x16_bf16((AA0).h, ba0.h, accA, 0,0,0);\
    accB = __builtin_amdgcn_mfma_f32_32x32x16_bf16((AA2).h, bb0.h, Z,    0,0,0);\
    accB = __builtin_amdgcn_mfma_f32_32x32x16_bf16((AA1).h, bb1.h, accB, 0,0,0);\
    accB = __builtin_amdgcn_mfma_f32_32x32x16_bf16((AA0).h, bb2.h, accB, 0,0,0);\
    accB = __builtin_amdgcn_mfma_f32_32x32x16_bf16((AA1).h, bb0.h, accB, 0,0,0);\
    accB = __builtin_amdgcn_mfma_f32_32x32x16_bf16((AA0).h, bb1.h, accB, 0,0,0);\
    accB = __builtin_amdgcn_mfma_f32_32x32x16_bf16((AA0).h, bb0.h, accB, 0,0,0);\
  } while (0)

// Max tree over 16 floats (v_max3-friendly).
#define MAXTREE(F, OUT)                                                        \
  const float _x0 = fmaxf(fmaxf(F[0], F[1]), F[2]);                            \
  const float _x1 = fmaxf(fmaxf(F[3], F[4]), F[5]);                            \
  const float _x2 = fmaxf(fmaxf(F[6], F[7]), F[8]);                            \
  const float _x3 = fmaxf(fmaxf(F[9], F[10]), F[11]);                          \
  const float _x4 = fmaxf(fmaxf(F[12], F[13]), F[14]);                         \
  const float OUT = fmaxf(fmaxf(fmaxf(_x0, _x1), _x2),                         \
                          fmaxf(fmaxf(_x3, _x4), F[15]));

// PV over one tile; E_EXPR(r) gives the exp2 argument for slot r.
#define PVBLK(TB, E_EXPR)                                                      \
  _Pragma("unroll")                                                            \
  for (int rg = 0; rg < 4; ++rg) {                                             \
    _Pragma("unroll")                                                          \
    for (int q = 0; q < 4; ++q) {                                              \
      const int r = rg*4 + q;                                                  \
      const float e = fast_exp2(E_EXPR);                                       \
      const float4 xv = xt[(TB) + rg*8 + hl*4 + q];                            \
      srun += e;                                                               \
      a0r = fmaf(e, xv.x, a0r);                                                \
      a1r = fmaf(e, xv.y, a1r);                                                \
      a2r = fmaf(e, xv.z, a2r);                                                \
    }                                                                          \
  }

// ---------------------------------------------------------------------------
// k_main (v12 = exact revert to v9, the session best: k_main 46.8 us, total
// 145.3 us): grid (768, 4), 256 thr = 4 waves; block owns one m, wave owns
// one 32-col c-tile. __launch_bounds__(256, 4) — NOT higher: R11 proved the
// pipelined body's true register demand exceeds the 6-waves/EU cap (~84);
// under cap 84 it spills wholesale (FETCH 119 MB / WRITE 239 MB scratch,
// 112 us). R9's reported VGPR=60 under cap 128 understates live-range peak.
// Structure: block-shared A-frags in LDS (R5), 1-deep MFMA software
// pipeline (R7), hoisted-Z acc init + fma drain fold + branch-free
// single-path online rescale (R9).
// A layout: row=lane&31, k=(lane>>5)*8+e, word pairs lo/hi. C/D (verified):
// col=lane&31, row=(reg&3)+8*(reg>>2)+4*(lane>>5).
// ---------------------------------------------------------------------------
__global__ __launch_bounds__(256, 4) void k_main(
    const float* __restrict__ x, const float* __restrict__ norms,
    const float* __restrict__ A3mT, const float* __restrict__ B3mT,
    float* __restrict__ Mp, float* __restrict__ Sp,
    float* __restrict__ A0p, float* __restrict__ A1p, float* __restrict__ A2p) {
  __shared__ __align__(16) float4 xt[CTILE];       // (x0,x1,x2,|x_n|), 3 KB
  __shared__ __align__(16) uint4 af[NT][3][64];    // A-frags: tile x split x lane, 18 KB
  const int tid = threadIdx.x;
  const int wid = tid >> 6;          // c-tile index 0..3
  const int lane = tid & 63;
  const int hl = lane >> 5;          // k-slice half
  const int ln = lane & 31;          // A row / B,C col
  const int m = blockIdx.x;
  const int chunk = blockIdx.y;
  const int c = wid*32 + ln;         // this lane's channel column

  // Stage this chunk's 192 n's (x, |x|) into LDS.
  for (int p = tid; p < CTILE; p += 256) {
    const int n = chunk*CTILE + p;
    xt[p] = make_float4(x[3*n], x[3*n+1], x[3*n+2], norms[n]);
  }

  const float u = norms[m];
  const float xm0 = x[3*m], xm1 = x[3*m+1], xm2 = x[3*m+2];
  const float uu = u*u;
  const float u1 = u, u2 = uu, u3 = uu*u, u4 = uu*uu;

  // ---- B-fragments: compile-time u-fold + split3 + MFMA-pack -------------
  Frag ba0, ba1, ba2, bb0, bb1, bb2;
  if (hl == 0) {
    fold_word<0,1>(A3mT, B3mT, c, u1,u2,u3,u4, ba0.u[0],ba1.u[0],ba2.u[0], bb0.u[0],bb1.u[0],bb2.u[0]);
    fold_word<2,3>(A3mT, B3mT, c, u1,u2,u3,u4, ba0.u[1],ba1.u[1],ba2.u[1], bb0.u[1],bb1.u[1],bb2.u[1]);
    fold_word<4,5>(A3mT, B3mT, c, u1,u2,u3,u4, ba0.u[2],ba1.u[2],ba2.u[2], bb0.u[2],bb1.u[2],bb2.u[2]);
    fold_word<6,7>(A3mT, B3mT, c, u1,u2,u3,u4, ba0.u[3],ba1.u[3],ba2.u[3], bb0.u[3],bb1.u[3],bb2.u[3]);
  } else {
    fold_word<8,9>  (A3mT, B3mT, c, u1,u2,u3,u4, ba0.u[0],ba1.u[0],ba2.u[0], bb0.u[0],bb1.u[0],bb2.u[0]);
    fold_word<10,11>(A3mT, B3mT, c, u1,u2,u3,u4, ba0.u[1],ba1.u[1],ba2.u[1], bb0.u[1],bb1.u[1],bb2.u[1]);
    fold_word<12,13>(A3mT, B3mT, c, u1,u2,u3,u4, ba0.u[2],ba1.u[2],ba2.u[2], bb0.u[2],bb1.u[2],bb2.u[2]);
    fold_word<14,15>(A3mT, B3mT, c, u1,u2,u3,u4, ba0.u[3],ba1.u[3],ba2.u[3], bb0.u[3],bb1.u[3],bb2.u[3]);
  }

  __syncthreads();   // xt staged

  // ---- Build phase: this wave builds A-frags for tiles wid, wid+4 --------
  for (int t = wid; t < NT; t += 4) {
    const float4 xn = xt[t*32 + ln];
    const float v = xn.w;
    const float dot = xm0*xn.x + xm1*xn.y + xm2*xn.z;
    const float d2 = uu + v*v - 2.f*dot;
    const float d = (d2 > 0.f) ? sqrtf(d2) : 0.f;   // grad-safe cdist semantics
    const float v2 = v*v, v3 = v2*v, v4 = v2*v2;
    const float dd = d*d, d3 = dd*d, d4 = dd*dd;
    float mono[8];
    if (hl == 0) {
      mono[0] = 1.f;   mono[1] = v;     mono[2] = v2;    mono[3] = v3;
      mono[4] = v4;    mono[5] = d;     mono[6] = d*v;   mono[7] = d*v2;
    } else {
      mono[0] = d*v3;  mono[1] = dd;    mono[2] = dd*v;  mono[3] = dd*v2;
      mono[4] = d3;    mono[5] = d3*v;  mono[6] = d4;    mono[7] = 0.f;
    }
    Frag A0f, A1f, A2f;
    #pragma unroll
    for (int p = 0; p < 4; ++p) {
      unsigned int l0, l1, l2, g0, g1, g2;
      split3(mono[2*p],   l0, l1, l2);
      split3(mono[2*p+1], g0, g1, g2);
      A0f.u[p] = l0 | (g0 << 16);
      A1f.u[p] = l1 | (g1 << 16);
      A2f.u[p] = l2 | (g2 << 16);
    }
    af[t][0][lane] = *(const uint4*)A0f.u;
    af[t][1][lane] = *(const uint4*)A1f.u;
    af[t][2][lane] = *(const uint4*)A2f.u;
  }

  __syncthreads();   // A-frags built

  float mrun, srun = 0.f, a0r = 0.f, a1r = 0.f, a2r = 0.f;

  f32x16 Z;
  #pragma unroll
  for (int r = 0; r < 16; ++r) Z[r] = 0.f;

  // ---- Pipeline prologue: tile 0's MFMAs in flight before the loop ----
  Frag A0f, A1f, A2f;
  *(uint4*)A0f.u = af[0][0][lane];
  *(uint4*)A1f.u = af[0][1][lane];
  *(uint4*)A2f.u = af[0][2][lane];
  f32x16 accA, accB;
  MFMA12Z(A0f, A1f, A2f);

  // ---- Tile 0 (peeled: no prior max) ----
  {
    *(uint4*)A0f.u = af[1][0][lane];
    *(uint4*)A1f.u = af[1][1][lane];
    *(uint4*)A2f.u = af[1][2][lane];
    float f[16];
    #pragma unroll
    for (int r = 0; r < 16; ++r) f[r] = accA[r]*accB[r];   // logits * log2e
    MFMA12Z(A0f, A1f, A2f);                                 // tile 1 in flight
    MAXTREE(f, hx0);
    mrun = hx0;
    PVBLK(0, f[r] - hx0);
  }

  for (int tile = 1; tile < NT; ++tile) {
    // Prefetch next tile's A-frags (issue only; consumed after f extract).
    if (tile + 1 < NT) {
      *(uint4*)A0f.u = af[tile+1][0][lane];
      *(uint4*)A1f.u = af[tile+1][1][lane];
      *(uint4*)A2f.u = af[tile+1][2][lane];
    }

    // Drain this tile's accumulators (waits on the in-flight MFMA chain);
    // -mrun folded into the drain fma.
    float f[16];
    #pragma unroll
    for (int r = 0; r < 16; ++r) f[r] = fmaf(accA[r], accB[r], -mrun);

    // Issue next tile's MFMAs now — they execute under this tile's softmax.
    if (tile + 1 < NT) MFMA12Z(A0f, A1f, A2f);

    // Branch-free online update: fxp = max growth (0 when max unchanged —
    // then sc = exp2(0) = 1 and the rescale is a no-op, exactly as R7).
    MAXTREE(f, fx);
    const float fxp = fmaxf(fx, 0.f);
    const float sc = fast_exp2(-fxp);
    mrun += fxp;
    srun *= sc; a0r *= sc; a1r *= sc; a2r *= sc;
    PVBLK(tile*32, f[r] - fxp);
  }

  // Merge the two lane-halves' online states (each covered half the rows).
  {
    const float om = __shfl_xor(mrun, 32);
    const float os = __shfl_xor(srun, 32);
    const float o0 = __shfl_xor(a0r, 32);
    const float o1 = __shfl_xor(a1r, 32);
    const float o2 = __shfl_xor(a2r, 32);
    const float M  = fmaxf(mrun, om);
    const float e1 = fast_exp2(mrun - M);
    const float e2 = fast_exp2(om - M);
    if (hl == 0) {
      const int idx = chunk*PAIR + m*CCH + c;
      Mp[idx]  = M;
      Sp[idx]  = fmaf(srun, e1, os*e2);
      A0p[idx] = fmaf(a0r, e1, o0*e2);
      A1p[idx] = fmaf(a1r, e1, o1*e2);
      A2p[idx] = fmaf(a2r, e1, o2*e2);
    }
  }
}

// ---------------------------------------------------------------------------
// k_fin (96 blocks x 256): merge NCHUNK=4 partials per (m,c), normalize,
// LDS-reduce 8 m-rows, atomics into apart; ticketed Wf contraction + out.
// ---------------------------------------------------------------------------
__global__ __launch_bounds__(256) void k_fin(
    const float* __restrict__ x,
    const float* __restrict__ Mp, const float* __restrict__ Sp,
    const float* __restrict__ A0p, const float* __restrict__ A1p,
    const float* __restrict__ A2p,
    const float* __restrict__ Wf,
    float* __restrict__ apart, unsigned int* __restrict__ ticket,
    float* __restrict__ out) {
  __shared__ float red2[2][3][CCH];
  __shared__ float red[CCH][6];
  __shared__ bool last;
  const int tid = threadIdx.x;
  const int ml = tid >> 7;
  const int c = tid & 127;

  float s0 = 0.f, s1 = 0.f, s2 = 0.f;
  #pragma unroll
  for (int j = 0; j < 4; ++j) {
    const int m = blockIdx.x*8 + ml*4 + j;
    const int gid = m*CCH + c;
    float mm[NCHUNK];
    #pragma unroll
    for (int p = 0; p < NCHUNK; ++p) mm[p] = Mp[p*PAIR + gid];
    float M = mm[0];
    #pragma unroll
    for (int p = 1; p < NCHUNK; ++p) M = fmaxf(M, mm[p]);
    float W = 0.f, g0 = 0.f, g1 = 0.f, g2 = 0.f;
    #pragma unroll
    for (int p = 0; p < NCHUNK; ++p) {
      const float ep = fast_exp2(mm[p] - M);
      W  = fmaf(Sp[p*PAIR+gid],  ep, W);
      g0 = fmaf(A0p[p*PAIR+gid], ep, g0);
      g1 = fmaf(A1p[p*PAIR+gid], ep, g1);
      g2 = fmaf(A2p[p*PAIR+gid], ep, g2);
    }
    const float inv = 1.f / W;
    s0 = fmaf(g0, inv, s0);
    s1 = fmaf(g1, inv, s1);
    s2 = fmaf(g2, inv, s2);
  }
  red2[ml][0][c] = s0; red2[ml][1][c] = s1; red2[ml][2][c] = s2;
  __syncthreads();
  for (int p = tid; p < NACC; p += 256) {
    const int i = p >> 7, cc = p & 127;
    atomicAdd(&apart[p], red2[0][i][cc] + red2[1][i][cc]);
  }
  __threadfence();
  __syncthreads();
  if (tid == 0) {
    const unsigned int old = atomicAdd(ticket, 1u);
    last = (old == FINB - 1);
  }
  __syncthreads();
  if (!last) return;
  __threadfence();

  if (tid < CCH) {
    const int cc = tid;
    const float a0 = __hip_atomic_load(&apart[cc],          __ATOMIC_RELAXED, __HIP_MEMORY_SCOPE_AGENT);
    const float a1 = __hip_atomic_load(&apart[CCH + cc],    __ATOMIC_RELAXED, __HIP_MEMORY_SCOPE_AGENT);
    const float a2 = __hip_atomic_load(&apart[2*CCH + cc],  __ATOMIC_RELAXED, __HIP_MEMORY_SCOPE_AGENT);
    const float w0 = Wf[cc], w1 = Wf[CCH + cc];
    red[cc][0] = w0*a0; red[cc][1] = w0*a1; red[cc][2] = w0*a2;
    red[cc][3] = w1*a0; red[cc][4] = w1*a1; red[cc][5] = w1*a2;
  }
  __syncthreads();
  if (tid < 6) {
    float s = 0.f;
    for (int k = 0; k < CCH; ++k) s += red[k][tid];
    out[3 + tid] = s;
  }
  if (tid < 3) out[tid] = x[tid];
}

// ---------------------------------------------------------------------------
extern "C" void kernel_launch(void* const* d_in, const int* in_sizes, int n_in,
                              void* d_out, int out_size, void* d_ws, size_t ws_size,
                              hipStream_t stream) {
  const float* x   = (const float*)d_in[0];
  const float* Wa1 = (const float*)d_in[1];
  const float* ba1 = (const float*)d_in[2];
  const float* Wb1 = (const float*)d_in[3];
  const float* bb1 = (const float*)d_in[4];
  const float* Wa2 = (const float*)d_in[5];
  const float* ba2 = (const float*)d_in[6];
  const float* Wb2 = (const float*)d_in[7];
  const float* bb2 = (const float*)d_in[8];
  const float* Wa3 = (const float*)d_in[9];
  const float* ba3 = (const float*)d_in[10];
  const float* Wb3 = (const float*)d_in[11];
  const float* bb3 = (const float*)d_in[12];
  const float* Wf  = (const float*)d_in[13];
  float* out = (float*)d_out;

  float* ws     = (float*)d_ws;
  float* norms  = ws;                      // 768
  float* C2m    = norms + NPTS;            // 128*36
  float* A3mT   = C2m   + CCH*NM4;         // 36*128
  float* B3mT   = A3mT  + NM4*CCH;         // 36*128
  float* Mp     = B3mT  + NM4*CCH;         // 4*98304
  float* Sp     = Mp    + NCHUNK*PAIR;
  float* A0p    = Sp    + NCHUNK*PAIR;
  float* A1p    = A0p   + NCHUNK*PAIR;
  float* A2p    = A1p   + NCHUNK*PAIR;
  float* apart  = A2p   + NCHUNK*PAIR;     // 384
  unsigned int* ticket = (unsigned int*)(apart + NACC);

  hipLaunchKernelGGL(k_fold12, dim3(CCH), dim3(128), 0, stream,
                     x, Wa1, ba1, Wb1, bb1, Wa2, ba2, Wb2, bb2,
                     norms, C2m, apart, ticket);
  hipLaunchKernelGGL(k_pre2, dim3(CCH), dim3(64), 0, stream,
                     Wa3, ba3, Wb3, bb3, C2m, A3mT, B3mT);
  hipLaunchKernelGGL(k_main, dim3(NPTS, NCHUNK), dim3(256), 0, stream,
                     x, norms, A3mT, B3mT, Mp, Sp, A0p, A1p, A2p);
  hipLaunchKernelGGL(k_fin, dim3(FINB), dim3(256), 0, stream,
                     x, Mp, Sp, A0p, A1p, A2p, Wf, apart, ticket, out);
}

// Round 13
// 147.364 us; speedup vs baseline: 1.4347x; 1.0016x over previous
//
#include <hip/hip_runtime.h>

#define NPTS 768
#define CCH  128
#define NM4  36    // 35 deg<=4 monomials in (d,u,v) + 1 pad
#define NM2  10    // deg<=2 monomials
#define NCHUNK 4   // n-chunks (192 n's each)
#define CTILE (NPTS/NCHUNK)   // 192 n per chunk
#define NT   (CTILE/32)       // 6 MFMA tiles per chunk
#define PAIR (NPTS*CCH)
#define NACC 384   // apart accumulator size (3 x 128)
#define FINB 96    // k_fin grid
#define LOG2E 1.4426950408889634f

typedef __attribute__((ext_vector_type(8))) short bf16x8;   // 8 bf16 in 4 VGPRs
typedef __attribute__((ext_vector_type(16))) float f32x16;  // MFMA 32x32 acc
union Frag { unsigned int u[4]; bf16x8 h; };

__device__ __forceinline__ float fast_exp2(float x) {
  return __builtin_amdgcn_exp2f(x);   // v_exp_f32 (base-2)
}

// Truncation-based 3-way bf16 split: x = h0 + h1 + h2 + eps, |eps| <= 2^-27 |x|.
__device__ __forceinline__ void split3(float x, unsigned int& h0,
                                       unsigned int& h1, unsigned int& h2) {
  const unsigned int b0 = __float_as_uint(x);
  h0 = b0 >> 16;
  const float r1 = x - __uint_as_float(b0 & 0xFFFF0000u);
  const unsigned int b1 = __float_as_uint(r1);
  h1 = b1 >> 16;
  const float r2 = r1 - __uint_as_float(b1 & 0xFFFF0000u);
  h2 = __float_as_uint(r2) >> 16;
}

// ---- monomial index helpers ------------------------------------------------
// (a,b,c) = (deg d, deg u, deg v), a outermost. Constexpr for the fold.
__device__ constexpr int ct4i(int a, int b, int c) {
  int t = 0;
  for (int aa = 0; aa < a; ++aa) t += (5 - aa) * (6 - aa) / 2;
  for (int bb = 0; bb < b; ++bb) t += (5 - a - bb);
  return t + c;
}
__device__ __forceinline__ int t2i(int a, int b, int c) {
  int t = 0;
  for (int aa = 0; aa < a; ++aa) t += (3 - aa) * (4 - aa) / 2;
  for (int bb = 0; bb < b; ++bb) t += (3 - a - bb);
  return t + c;
}
// (i,j) = (deg d, deg v) for the 15-term u-folded basis, i-major (t15 = pad)
__device__ constexpr int tdi(int t) { return t<5?0 : t<9?1 : t<12?2 : t<14?3 : 4; }
__device__ constexpr int tdj(int t) { return t<5?t : t<9?t-5 : t<12?t-9 : t<14?t-12 : 0; }

// Compile-time u-fold of one basis monomial t: s = sum_b coef[t4i(i,b,j)] u^b.
template<int T>
__device__ __forceinline__ void fold_one(const float* __restrict__ A3,
                                         const float* __restrict__ B3, int c,
                                         float u1, float u2, float u3, float u4,
                                         float& sa, float& sb) {
  if constexpr (T >= 15) { sa = 0.f; sb = 0.f; }
  else {
    constexpr int I = tdi(T), J = tdj(T);
    sa = A3[ct4i(I,0,J)*CCH + c];
    sb = B3[ct4i(I,0,J)*CCH + c];
    if constexpr (I+J+1 <= 4) { sa = fmaf(A3[ct4i(I,1,J)*CCH+c], u1, sa);
                                sb = fmaf(B3[ct4i(I,1,J)*CCH+c], u1, sb); }
    if constexpr (I+J+2 <= 4) { sa = fmaf(A3[ct4i(I,2,J)*CCH+c], u2, sa);
                                sb = fmaf(B3[ct4i(I,2,J)*CCH+c], u2, sb); }
    if constexpr (I+J+3 <= 4) { sa = fmaf(A3[ct4i(I,3,J)*CCH+c], u3, sa);
                                sb = fmaf(B3[ct4i(I,3,J)*CCH+c], u3, sb); }
    if constexpr (I+J+4 <= 4) { sa = fmaf(A3[ct4i(I,4,J)*CCH+c], u4, sa);
                                sb = fmaf(B3[ct4i(I,4,J)*CCH+c], u4, sb); }
  }
}

// One packed MFMA B-word (k=TLO lo16, k=THI hi16) x 3 splits x {A,B polys}.
template<int TLO, int THI>
__device__ __forceinline__ void fold_word(const float* __restrict__ A3,
                                          const float* __restrict__ B3, int c,
                                          float u1, float u2, float u3, float u4,
                                          unsigned int& wa0, unsigned int& wa1,
                                          unsigned int& wa2, unsigned int& wb0,
                                          unsigned int& wb1, unsigned int& wb2) {
  float salo, sblo, sahi, sbhi;
  fold_one<TLO>(A3, B3, c, u1, u2, u3, u4, salo, sblo);
  fold_one<THI>(A3, B3, c, u1, u2, u3, u4, sahi, sbhi);
  salo *= LOG2E; sahi *= LOG2E;             // log2e folded into A-poly
  unsigned int a0,a1,a2, c0,c1,c2, b0,b1,b2, d0,d1,d2;
  split3(salo, a0, a1, a2); split3(sahi, c0, c1, c2);
  split3(sblo, b0, b1, b2); split3(sbhi, d0, d1, d2);
  wa0 = a0 | (c0 << 16); wa1 = a1 | (c1 << 16); wa2 = a2 | (c2 << 16);
  wb0 = b0 | (d0 << 16); wb1 = b1 | (d1 << 16); wb2 = b2 | (d2 << 16);
}

// ---------------------------------------------------------------------------
// k_fold12 — layer-1/2 fold (unchanged).
// ---------------------------------------------------------------------------
__global__ __launch_bounds__(128) void k_fold12(
    const float* __restrict__ x,
    const float* __restrict__ Wa1, const float* __restrict__ ba1,
    const float* __restrict__ Wb1, const float* __restrict__ bb1,
    const float* __restrict__ Wa2, const float* __restrict__ ba2,
    const float* __restrict__ Wb2, const float* __restrict__ bb2,
    float* __restrict__ norms, float* __restrict__ C2m,
    float* __restrict__ apart, unsigned int* __restrict__ ticket) {
  __shared__ float sA[128][NM2];
  __shared__ float sB[128][NM2];
  const int c = blockIdx.x;
  const int k = threadIdx.x;

  if (c < 6) {
    const int i = c*128 + k;
    const float p0 = x[3*i], p1 = x[3*i+1], p2 = x[3*i+2];
    norms[i] = sqrtf(p0*p0 + p1*p1 + p2*p2);
  }
  if (c == 6) {
    apart[k] = 0.f; apart[CCH + k] = 0.f; apart[2*CCH + k] = 0.f;
    if (k == 0) *ticket = 0u;
  }

  {
    const float A0 = Wa1[3*k], A1 = Wa1[3*k+1], A2c = Wa1[3*k+2], A3 = ba1[k];
    const float B0 = Wb1[3*k], B1 = Wb1[3*k+1], B2c = Wb1[3*k+2], B3 = bb1[k];
    const float g0 = A3*B3;              // 1
    const float g1 = A2c*B3 + A3*B2c;    // v
    const float g2 = A2c*B2c;            // v^2
    const float g3 = A1*B3 + A3*B1;      // u
    const float g4 = A1*B2c + A2c*B1;    // u v
    const float g5 = A1*B1;              // u^2
    const float g6 = A0*B3 + A3*B0;      // d
    const float g7 = A0*B2c + A2c*B0;    // d v
    const float g8 = A0*B1 + A1*B0;      // d u
    const float g9 = A0*B0;              // d^2
    const float wa = Wa2[c*CCH + k];
    const float wb = Wb2[c*CCH + k];
    sA[k][0] = wa*g0; sB[k][0] = wb*g0;
    sA[k][1] = wa*g1; sB[k][1] = wb*g1;
    sA[k][2] = wa*g2; sB[k][2] = wb*g2;
    sA[k][3] = wa*g3; sB[k][3] = wb*g3;
    sA[k][4] = wa*g4; sB[k][4] = wb*g4;
    sA[k][5] = wa*g5; sB[k][5] = wb*g5;
    sA[k][6] = wa*g6; sB[k][6] = wb*g6;
    sA[k][7] = wa*g7; sB[k][7] = wb*g7;
    sA[k][8] = wa*g8; sB[k][8] = wb*g8;
    sA[k][9] = wa*g9; sB[k][9] = wb*g9;
  }
  __syncthreads();

  for (int s = 64; s >= 1; s >>= 1) {
    if (k < s) {
      for (int t = 0; t < NM2; ++t) {
        sA[k][t] += sA[k+s][t];
        sB[k][t] += sB[k+s][t];
      }
    }
    __syncthreads();
  }
  if (k == 0) {
    sA[0][0] += ba2[c];
    sB[0][0] += bb2[c];
  }
  __syncthreads();

  if (k < 35) {
    int rem = k, a = 0;
    while (rem >= (5 - a)*(6 - a)/2) { rem -= (5 - a)*(6 - a)/2; ++a; }
    int b = 0;
    while (rem >= 5 - a - b) { rem -= 5 - a - b; ++b; }
    const int cc = rem;
    float s = 0.f;
    const int deg = a + b + cc;
    for (int a1 = 0; a1 <= a && a1 <= 2; ++a1)
      for (int b1 = 0; b1 <= b && b1 <= 2; ++b1)
        for (int c1 = 0; c1 <= cc && c1 <= 2; ++c1) {
          const int d1 = a1 + b1 + c1;
          if (d1 <= 2 && (deg - d1) <= 2)
            s += sA[0][t2i(a1, b1, c1)]
               * sB[0][t2i(a - a1, b - b1, cc - c1)];
        }
    C2m[c*NM4 + k] = s;
  }
  if (k == 35) C2m[c*NM4 + 35] = 0.f;
}

// ---------------------------------------------------------------------------
// k_pre2 (128 blocks x 64 thr): A3mT/B3mT = layer-3 fold, transposed (36x128).
// ---------------------------------------------------------------------------
__global__ void k_pre2(const float* __restrict__ Wa3, const float* __restrict__ ba3,
                       const float* __restrict__ Wb3, const float* __restrict__ bb3,
                       const float* __restrict__ C2m,
                       float* __restrict__ A3mT, float* __restrict__ B3mT) {
  const int c = blockIdx.x;
  const int j = threadIdx.x;
  if (j >= NM4) return;
  float sa = 0.f, sb = 0.f;
  if (j < 35) {
    for (int k = 0; k < CCH; ++k) {
      const float v = C2m[k*NM4 + j];
      sa += Wa3[c*CCH + k] * v;
      sb += Wb3[c*CCH + k] * v;
    }
    if (j == 0) { sa += ba3[c]; sb += bb3[c]; }
  }
  A3mT[j*CCH + c] = sa;
  B3mT[j*CCH + c] = sb;
}

// 12 MFMAs of one tile; first of each chain consumes the hoisted zero Z
// (no per-tile acc re-zero — saves 32 v_mov/tile).
#define MFMA12Z(AA0, AA1, AA2)                                                 \
  do {                                                                         \
    accA = __builtin_amdgcn_mfma_f32_32x32x16_bf16((AA2).h, ba0.h, Z,    0,0,0);\
    accA = __builtin_amdgcn_mfma_f32_32x32x16_bf16((AA1).h, ba1.h, accA, 0,0,0);\
    accA = __builtin_amdgcn_mfma_f32_32x32x16_bf16((AA0).h, ba2.h, accA, 0,0,0);\
    accA = __builtin_amdgcn_mfma_f32_32x32x16_bf16((AA1).h, ba0.h, accA, 0,0,0);\
    accA = __builtin_amdgcn_mfma_f32_32x32x16_bf16((AA0).h, ba1.h, accA, 0,0,0);\
    accA = __builtin_amdgcn_mfma_f32_32x32x16_bf16((AA0).h, ba0.h, accA, 0,0,0);\
    accB = __builtin_amdgcn_mfma_f32_32x32x16_bf16((AA2).h, bb0.h, Z,    0,0,0);\
    accB = __builtin_amdgcn_mfma_f32_32x32x16_bf16((AA1).h, bb1.h, accB, 0,0,0);\
    accB = __builtin_amdgcn_mfma_f32_32x32x16_bf16((AA0).h, bb2.h, accB, 0,0,0);\
    accB = __builtin_amdgcn_mfma_f32_32x32x16_bf16((AA1).h, bb0.h, accB, 0,0,0);\
    accB = __builtin_amdgcn_mfma_f32_32x32x16_bf16((AA0).h, bb1.h, accB, 0,0,0);\
    accB = __builtin_amdgcn_mfma_f32_32x32x16_bf16((AA0).h, bb0.h, accB, 0,0,0);\
  } while (0)

// Max tree over 16 floats (v_max3-friendly).
#define MAXTREE(F, OUT)                                                        \
  const float _x0 = fmaxf(fmaxf(F[0], F[1]), F[2]);                            \
  const float _x1 = fmaxf(fmaxf(F[3], F[4]), F[5]);                            \
  const float _x2 = fmaxf(fmaxf(F[6], F[7]), F[8]);                            \
  const float _x3 = fmaxf(fmaxf(F[9], F[10]), F[11]);                          \
  const float _x4 = fmaxf(fmaxf(F[12], F[13]), F[14]);                         \
  const float OUT = fmaxf(fmaxf(fmaxf(_x0, _x1), _x2),                         \
                          fmaxf(fmaxf(_x3, _x4), F[15]));

// PV over one tile into 2-way split accumulators (rg 0-1 -> [0], 2-3 -> [1]):
// halves the serial fma chain depth (16 -> 8) on the per-tile critical path.
// Index rg>>1 is compile-time after unroll (rule-#20 safe).
#define PVBLK(TB, E_EXPR)                                                      \
  _Pragma("unroll")                                                            \
  for (int rg = 0; rg < 4; ++rg) {                                             \
    _Pragma("unroll")                                                          \
    for (int q = 0; q < 4; ++q) {                                              \
      const int r = rg*4 + q;                                                  \
      const int h_ = rg >> 1;                                                  \
      const float e = fast_exp2(E_EXPR);                                       \
      const float4 xv = xt[(TB) + rg*8 + hl*4 + q];                            \
      sr[h_] += e;                                                             \
      a0[h_] = fmaf(e, xv.x, a0[h_]);                                          \
      a1[h_] = fmaf(e, xv.y, a1[h_]);                                          \
      a2[h_] = fmaf(e, xv.z, a2[h_]);                                          \
    }                                                                          \
  }

// ---------------------------------------------------------------------------
// k_main (v13 = v9/v12 + 2-way split PV accumulators): grid (768, 4), 256
// thr = 4 waves; block owns one m, wave owns one 32-col c-tile.
// R12 confirmed the latency plateau (VALU 60%, MFMA 25%, occupancy 31% at
// the register-capped 4 waves/SIMD). The remaining safe lever is the
// per-tile SERIAL chain: srun/a0r/a1r/a2r each accumulated 16 exp-terms
// in a 16-deep fma chain (~64 cyc) after maxtree+sc-exp2. v13 splits each
// into 2 chains (8-deep), merged once after the loop. +4 VGPR, +4 rescale
// muls/tile, pure reassociation. Everything else byte-for-byte v12.
// __launch_bounds__(256,4) — R11 proved higher bounds spill.
// A layout: row=lane&31, k=(lane>>5)*8+e, word pairs lo/hi. C/D (verified):
// col=lane&31, row=(reg&3)+8*(reg>>2)+4*(lane>>5).
// ---------------------------------------------------------------------------
__global__ __launch_bounds__(256, 4) void k_main(
    const float* __restrict__ x, const float* __restrict__ norms,
    const float* __restrict__ A3mT, const float* __restrict__ B3mT,
    float* __restrict__ Mp, float* __restrict__ Sp,
    float* __restrict__ A0p, float* __restrict__ A1p, float* __restrict__ A2p) {
  __shared__ __align__(16) float4 xt[CTILE];       // (x0,x1,x2,|x_n|), 3 KB
  __shared__ __align__(16) uint4 af[NT][3][64];    // A-frags: tile x split x lane, 18 KB
  const int tid = threadIdx.x;
  const int wid = tid >> 6;          // c-tile index 0..3
  const int lane = tid & 63;
  const int hl = lane >> 5;          // k-slice half
  const int ln = lane & 31;          // A row / B,C col
  const int m = blockIdx.x;
  const int chunk = blockIdx.y;
  const int c = wid*32 + ln;         // this lane's channel column

  // Stage this chunk's 192 n's (x, |x|) into LDS.
  for (int p = tid; p < CTILE; p += 256) {
    const int n = chunk*CTILE + p;
    xt[p] = make_float4(x[3*n], x[3*n+1], x[3*n+2], norms[n]);
  }

  const float u = norms[m];
  const float xm0 = x[3*m], xm1 = x[3*m+1], xm2 = x[3*m+2];
  const float uu = u*u;
  const float u1 = u, u2 = uu, u3 = uu*u, u4 = uu*uu;

  // ---- B-fragments: compile-time u-fold + split3 + MFMA-pack -------------
  Frag ba0, ba1, ba2, bb0, bb1, bb2;
  if (hl == 0) {
    fold_word<0,1>(A3mT, B3mT, c, u1,u2,u3,u4, ba0.u[0],ba1.u[0],ba2.u[0], bb0.u[0],bb1.u[0],bb2.u[0]);
    fold_word<2,3>(A3mT, B3mT, c, u1,u2,u3,u4, ba0.u[1],ba1.u[1],ba2.u[1], bb0.u[1],bb1.u[1],bb2.u[1]);
    fold_word<4,5>(A3mT, B3mT, c, u1,u2,u3,u4, ba0.u[2],ba1.u[2],ba2.u[2], bb0.u[2],bb1.u[2],bb2.u[2]);
    fold_word<6,7>(A3mT, B3mT, c, u1,u2,u3,u4, ba0.u[3],ba1.u[3],ba2.u[3], bb0.u[3],bb1.u[3],bb2.u[3]);
  } else {
    fold_word<8,9>  (A3mT, B3mT, c, u1,u2,u3,u4, ba0.u[0],ba1.u[0],ba2.u[0], bb0.u[0],bb1.u[0],bb2.u[0]);
    fold_word<10,11>(A3mT, B3mT, c, u1,u2,u3,u4, ba0.u[1],ba1.u[1],ba2.u[1], bb0.u[1],bb1.u[1],bb2.u[1]);
    fold_word<12,13>(A3mT, B3mT, c, u1,u2,u3,u4, ba0.u[2],ba1.u[2],ba2.u[2], bb0.u[2],bb1.u[2],bb2.u[2]);
    fold_word<14,15>(A3mT, B3mT, c, u1,u2,u3,u4, ba0.u[3],ba1.u[3],ba2.u[3], bb0.u[3],bb1.u[3],bb2.u[3]);
  }

  __syncthreads();   // xt staged

  // ---- Build phase: this wave builds A-frags for tiles wid, wid+4 --------
  for (int t = wid; t < NT; t += 4) {
    const float4 xn = xt[t*32 + ln];
    const float v = xn.w;
    const float dot = xm0*xn.x + xm1*xn.y + xm2*xn.z;
    const float d2 = uu + v*v - 2.f*dot;
    const float d = (d2 > 0.f) ? sqrtf(d2) : 0.f;   // grad-safe cdist semantics
    const float v2 = v*v, v3 = v2*v, v4 = v2*v2;
    const float dd = d*d, d3 = dd*d, d4 = dd*dd;
    float mono[8];
    if (hl == 0) {
      mono[0] = 1.f;   mono[1] = v;     mono[2] = v2;    mono[3] = v3;
      mono[4] = v4;    mono[5] = d;     mono[6] = d*v;   mono[7] = d*v2;
    } else {
      mono[0] = d*v3;  mono[1] = dd;    mono[2] = dd*v;  mono[3] = dd*v2;
      mono[4] = d3;    mono[5] = d3*v;  mono[6] = d4;    mono[7] = 0.f;
    }
    Frag A0f, A1f, A2f;
    #pragma unroll
    for (int p = 0; p < 4; ++p) {
      unsigned int l0, l1, l2, g0, g1, g2;
      split3(mono[2*p],   l0, l1, l2);
      split3(mono[2*p+1], g0, g1, g2);
      A0f.u[p] = l0 | (g0 << 16);
      A1f.u[p] = l1 | (g1 << 16);
      A2f.u[p] = l2 | (g2 << 16);
    }
    af[t][0][lane] = *(const uint4*)A0f.u;
    af[t][1][lane] = *(const uint4*)A1f.u;
    af[t][2][lane] = *(const uint4*)A2f.u;
  }

  __syncthreads();   // A-frags built

  float mrun;
  float sr[2] = {0.f, 0.f};
  float a0[2] = {0.f, 0.f};
  float a1[2] = {0.f, 0.f};
  float a2[2] = {0.f, 0.f};

  f32x16 Z;
  #pragma unroll
  for (int r = 0; r < 16; ++r) Z[r] = 0.f;

  // ---- Pipeline prologue: tile 0's MFMAs in flight before the loop ----
  Frag A0f, A1f, A2f;
  *(uint4*)A0f.u = af[0][0][lane];
  *(uint4*)A1f.u = af[0][1][lane];
  *(uint4*)A2f.u = af[0][2][lane];
  f32x16 accA, accB;
  MFMA12Z(A0f, A1f, A2f);

  // ---- Tile 0 (peeled: no prior max) ----
  {
    *(uint4*)A0f.u = af[1][0][lane];
    *(uint4*)A1f.u = af[1][1][lane];
    *(uint4*)A2f.u = af[1][2][lane];
    float f[16];
    #pragma unroll
    for (int r = 0; r < 16; ++r) f[r] = accA[r]*accB[r];   // logits * log2e
    MFMA12Z(A0f, A1f, A2f);                                 // tile 1 in flight
    MAXTREE(f, hx0);
    mrun = hx0;
    PVBLK(0, f[r] - hx0);
  }

  for (int tile = 1; tile < NT; ++tile) {
    // Prefetch next tile's A-frags (issue only; consumed after f extract).
    if (tile + 1 < NT) {
      *(uint4*)A0f.u = af[tile+1][0][lane];
      *(uint4*)A1f.u = af[tile+1][1][lane];
      *(uint4*)A2f.u = af[tile+1][2][lane];
    }

    // Drain this tile's accumulators (waits on the in-flight MFMA chain);
    // -mrun folded into the drain fma.
    float f[16];
    #pragma unroll
    for (int r = 0; r < 16; ++r) f[r] = fmaf(accA[r], accB[r], -mrun);

    // Issue next tile's MFMAs now — they execute under this tile's softmax.
    if (tile + 1 < NT) MFMA12Z(A0f, A1f, A2f);

    // Branch-free online update: fxp = max growth (0 when max unchanged —
    // then sc = exp2(0) = 1 and the rescale is a no-op).
    MAXTREE(f, fx);
    const float fxp = fmaxf(fx, 0.f);
    const float sc = fast_exp2(-fxp);
    mrun += fxp;
    sr[0] *= sc; a0[0] *= sc; a1[0] *= sc; a2[0] *= sc;
    sr[1] *= sc; a0[1] *= sc; a1[1] *= sc; a2[1] *= sc;
    PVBLK(tile*32, f[r] - fxp);
  }

  // Merge the split accumulators, then the two lane-halves' online states.
  {
    const float srun = sr[0] + sr[1];
    const float a0r = a0[0] + a0[1];
    const float a1r = a1[0] + a1[1];
    const float a2r = a2[0] + a2[1];
    const float om = __shfl_xor(mrun, 32);
    const float os = __shfl_xor(srun, 32);
    const float o0 = __shfl_xor(a0r, 32);
    const float o1 = __shfl_xor(a1r, 32);
    const float o2 = __shfl_xor(a2r, 32);
    const float M  = fmaxf(mrun, om);
    const float e1 = fast_exp2(mrun - M);
    const float e2 = fast_exp2(om - M);
    if (hl == 0) {
      const int idx = chunk*PAIR + m*CCH + c;
      Mp[idx]  = M;
      Sp[idx]  = fmaf(srun, e1, os*e2);
      A0p[idx] = fmaf(a0r, e1, o0*e2);
      A1p[idx] = fmaf(a1r, e1, o1*e2);
      A2p[idx] = fmaf(a2r, e1, o2*e2);
    }
  }
}

// ---------------------------------------------------------------------------
// k_fin (96 blocks x 256): merge NCHUNK=4 partials per (m,c), normalize,
// LDS-reduce 8 m-rows, atomics into apart; ticketed Wf contraction + out.
// ---------------------------------------------------------------------------
__global__ __launch_bounds__(256) void k_fin(
    const float* __restrict__ x,
    const float* __restrict__ Mp, const float* __restrict__ Sp,
    const float* __restrict__ A0p, const float* __restrict__ A1p,
    const float* __restrict__ A2p,
    const float* __restrict__ Wf,
    float* __restrict__ apart, unsigned int* __restrict__ ticket,
    float* __restrict__ out) {
  __shared__ float red2[2][3][CCH];
  __shared__ float red[CCH][6];
  __shared__ bool last;
  const int tid = threadIdx.x;
  const int ml = tid >> 7;
  const int c = tid & 127;

  float s0 = 0.f, s1 = 0.f, s2 = 0.f;
  #pragma unroll
  for (int j = 0; j < 4; ++j) {
    const int m = blockIdx.x*8 + ml*4 + j;
    const int gid = m*CCH + c;
    float mm[NCHUNK];
    #pragma unroll
    for (int p = 0; p < NCHUNK; ++p) mm[p] = Mp[p*PAIR + gid];
    float M = mm[0];
    #pragma unroll
    for (int p = 1; p < NCHUNK; ++p) M = fmaxf(M, mm[p]);
    float W = 0.f, g0 = 0.f, g1 = 0.f, g2 = 0.f;
    #pragma unroll
    for (int p = 0; p < NCHUNK; ++p) {
      const float ep = fast_exp2(mm[p] - M);
      W  = fmaf(Sp[p*PAIR+gid],  ep, W);
      g0 = fmaf(A0p[p*PAIR+gid], ep, g0);
      g1 = fmaf(A1p[p*PAIR+gid], ep, g1);
      g2 = fmaf(A2p[p*PAIR+gid], ep, g2);
    }
    const float inv = 1.f / W;
    s0 = fmaf(g0, inv, s0);
    s1 = fmaf(g1, inv, s1);
    s2 = fmaf(g2, inv, s2);
  }
  red2[ml][0][c] = s0; red2[ml][1][c] = s1; red2[ml][2][c] = s2;
  __syncthreads();
  for (int p = tid; p < NACC; p += 256) {
    const int i = p >> 7, cc = p & 127;
    atomicAdd(&apart[p], red2[0][i][cc] + red2[1][i][cc]);
  }
  __threadfence();
  __syncthreads();
  if (tid == 0) {
    const unsigned int old = atomicAdd(ticket, 1u);
    last = (old == FINB - 1);
  }
  __syncthreads();
  if (!last) return;
  __threadfence();

  if (tid < CCH) {
    const int cc = tid;
    const float a0 = __hip_atomic_load(&apart[cc],          __ATOMIC_RELAXED, __HIP_MEMORY_SCOPE_AGENT);
    const float a1 = __hip_atomic_load(&apart[CCH + cc],    __ATOMIC_RELAXED, __HIP_MEMORY_SCOPE_AGENT);
    const float a2 = __hip_atomic_load(&apart[2*CCH + cc],  __ATOMIC_RELAXED, __HIP_MEMORY_SCOPE_AGENT);
    const float w0 = Wf[cc], w1 = Wf[CCH + cc];
    red[cc][0] = w0*a0; red[cc][1] = w0*a1; red[cc][2] = w0*a2;
    red[cc][3] = w1*a0; red[cc][4] = w1*a1; red[cc][5] = w1*a2;
  }
  __syncthreads();
  if (tid < 6) {
    float s = 0.f;
    for (int k = 0; k < CCH; ++k) s += red[k][tid];
    out[3 + tid] = s;
  }
  if (tid < 3) out[tid] = x[tid];
}

// ---------------------------------------------------------------------------
extern "C" void kernel_launch(void* const* d_in, const int* in_sizes, int n_in,
                              void* d_out, int out_size, void* d_ws, size_t ws_size,
                              hipStream_t stream) {
  const float* x   = (const float*)d_in[0];
  const float* Wa1 = (const float*)d_in[1];
  const float* ba1 = (const float*)d_in[2];
  const float* Wb1 = (const float*)d_in[3];
  const float* bb1 = (const float*)d_in[4];
  const float* Wa2 = (const float*)d_in[5];
  const float* ba2 = (const float*)d_in[6];
  const float* Wb2 = (const float*)d_in[7];
  const float* bb2 = (const float*)d_in[8];
  const float* Wa3 = (const float*)d_in[9];
  const float* ba3 = (const float*)d_in[10];
  const float* Wb3 = (const float*)d_in[11];
  const float* bb3 = (const float*)d_in[12];
  const float* Wf  = (const float*)d_in[13];
  float* out = (float*)d_out;

  float* ws     = (float*)d_ws;
  float* norms  = ws;                      // 768
  float* C2m    = norms + NPTS;            // 128*36
  float* A3mT   = C2m   + CCH*NM4;         // 36*128
  float* B3mT   = A3mT  + NM4*CCH;         // 36*128
  float* Mp     = B3mT  + NM4*CCH;         // 4*98304
  float* Sp     = Mp    + NCHUNK*PAIR;
  float* A0p    = Sp    + NCHUNK*PAIR;
  float* A1p    = A0p   + NCHUNK*PAIR;
  float* A2p    = A1p   + NCHUNK*PAIR;
  float* apart  = A2p   + NCHUNK*PAIR;     // 384
  unsigned int* ticket = (unsigned int*)(apart + NACC);

  hipLaunchKernelGGL(k_fold12, dim3(CCH), dim3(128), 0, stream,
                     x, Wa1, ba1, Wb1, bb1, Wa2, ba2, Wb2, bb2,
                     norms, C2m, apart, ticket);
  hipLaunchKernelGGL(k_pre2, dim3(CCH), dim3(64), 0, stream,
                     Wa3, ba3, Wb3, bb3, C2m, A3mT, B3mT);
  hipLaunchKernelGGL(k_main, dim3(NPTS, NCHUNK), dim3(256), 0, stream,
                     x, norms, A3mT, B3mT, Mp, Sp, A0p, A1p, A2p);
  hipLaunchKernelGGL(k_fin, dim3(FINB), dim3(256), 0, stream,
                     x, Mp, Sp, A0p, A1p, A2p, Wf, apart, ticket, out);
}

// Round 14
// 144.561 us; speedup vs baseline: 1.4626x; 1.0194x over previous
//
#include <hip/hip_runtime.h>

#define NPTS 768
#define CCH  128
#define NM4  36    // 35 deg<=4 monomials in (d,u,v) + 1 pad
#define NM2  10    // deg<=2 monomials
#define NCHUNK 4   // n-chunks (192 n's each)
#define CTILE (NPTS/NCHUNK)   // 192 n per chunk
#define NT   (CTILE/32)       // 6 MFMA tiles per chunk
#define PAIR (NPTS*CCH)
#define NACC 384   // apart accumulator size (3 x 128)
#define FINB 96    // k_fin grid
#define LOG2E 1.4426950408889634f

typedef __attribute__((ext_vector_type(8))) short bf16x8;   // 8 bf16 in 4 VGPRs
typedef __attribute__((ext_vector_type(16))) float f32x16;  // MFMA 32x32 acc
union Frag { unsigned int u[4]; bf16x8 h; };

__device__ __forceinline__ float fast_exp2(float x) {
  return __builtin_amdgcn_exp2f(x);   // v_exp_f32 (base-2)
}

// Truncation-based 3-way bf16 split: x = h0 + h1 + h2 + eps, |eps| <= 2^-27 |x|.
__device__ __forceinline__ void split3(float x, unsigned int& h0,
                                       unsigned int& h1, unsigned int& h2) {
  const unsigned int b0 = __float_as_uint(x);
  h0 = b0 >> 16;
  const float r1 = x - __uint_as_float(b0 & 0xFFFF0000u);
  const unsigned int b1 = __float_as_uint(r1);
  h1 = b1 >> 16;
  const float r2 = r1 - __uint_as_float(b1 & 0xFFFF0000u);
  h2 = __float_as_uint(r2) >> 16;
}

// ---- monomial index helpers ------------------------------------------------
// (a,b,c) = (deg d, deg u, deg v), a outermost. Constexpr for the fold.
__device__ constexpr int ct4i(int a, int b, int c) {
  int t = 0;
  for (int aa = 0; aa < a; ++aa) t += (5 - aa) * (6 - aa) / 2;
  for (int bb = 0; bb < b; ++bb) t += (5 - a - bb);
  return t + c;
}
__device__ __forceinline__ int t2i(int a, int b, int c) {
  int t = 0;
  for (int aa = 0; aa < a; ++aa) t += (3 - aa) * (4 - aa) / 2;
  for (int bb = 0; bb < b; ++bb) t += (3 - a - bb);
  return t + c;
}
// (i,j) = (deg d, deg v) for the 15-term u-folded basis, i-major (t15 = pad)
__device__ constexpr int tdi(int t) { return t<5?0 : t<9?1 : t<12?2 : t<14?3 : 4; }
__device__ constexpr int tdj(int t) { return t<5?t : t<9?t-5 : t<12?t-9 : t<14?t-12 : 0; }

// Compile-time u-fold of one basis monomial t: s = sum_b coef[t4i(i,b,j)] u^b.
template<int T>
__device__ __forceinline__ void fold_one(const float* __restrict__ A3,
                                         const float* __restrict__ B3, int c,
                                         float u1, float u2, float u3, float u4,
                                         float& sa, float& sb) {
  if constexpr (T >= 15) { sa = 0.f; sb = 0.f; }
  else {
    constexpr int I = tdi(T), J = tdj(T);
    sa = A3[ct4i(I,0,J)*CCH + c];
    sb = B3[ct4i(I,0,J)*CCH + c];
    if constexpr (I+J+1 <= 4) { sa = fmaf(A3[ct4i(I,1,J)*CCH+c], u1, sa);
                                sb = fmaf(B3[ct4i(I,1,J)*CCH+c], u1, sb); }
    if constexpr (I+J+2 <= 4) { sa = fmaf(A3[ct4i(I,2,J)*CCH+c], u2, sa);
                                sb = fmaf(B3[ct4i(I,2,J)*CCH+c], u2, sb); }
    if constexpr (I+J+3 <= 4) { sa = fmaf(A3[ct4i(I,3,J)*CCH+c], u3, sa);
                                sb = fmaf(B3[ct4i(I,3,J)*CCH+c], u3, sb); }
    if constexpr (I+J+4 <= 4) { sa = fmaf(A3[ct4i(I,4,J)*CCH+c], u4, sa);
                                sb = fmaf(B3[ct4i(I,4,J)*CCH+c], u4, sb); }
  }
}

// One packed MFMA B-word (k=TLO lo16, k=THI hi16) x 3 splits x {A,B polys}.
template<int TLO, int THI>
__device__ __forceinline__ void fold_word(const float* __restrict__ A3,
                                          const float* __restrict__ B3, int c,
                                          float u1, float u2, float u3, float u4,
                                          unsigned int& wa0, unsigned int& wa1,
                                          unsigned int& wa2, unsigned int& wb0,
                                          unsigned int& wb1, unsigned int& wb2) {
  float salo, sblo, sahi, sbhi;
  fold_one<TLO>(A3, B3, c, u1, u2, u3, u4, salo, sblo);
  fold_one<THI>(A3, B3, c, u1, u2, u3, u4, sahi, sbhi);
  salo *= LOG2E; sahi *= LOG2E;             // log2e folded into A-poly
  unsigned int a0,a1,a2, c0,c1,c2, b0,b1,b2, d0,d1,d2;
  split3(salo, a0, a1, a2); split3(sahi, c0, c1, c2);
  split3(sblo, b0, b1, b2); split3(sbhi, d0, d1, d2);
  wa0 = a0 | (c0 << 16); wa1 = a1 | (c1 << 16); wa2 = a2 | (c2 << 16);
  wb0 = b0 | (d0 << 16); wb1 = b1 | (d1 << 16); wb2 = b2 | (d2 << 16);
}

// ---------------------------------------------------------------------------
// k_fold12 — layer-1/2 fold (unchanged).
// ---------------------------------------------------------------------------
__global__ __launch_bounds__(128) void k_fold12(
    const float* __restrict__ x,
    const float* __restrict__ Wa1, const float* __restrict__ ba1,
    const float* __restrict__ Wb1, const float* __restrict__ bb1,
    const float* __restrict__ Wa2, const float* __restrict__ ba2,
    const float* __restrict__ Wb2, const float* __restrict__ bb2,
    float* __restrict__ norms, float* __restrict__ C2m,
    float* __restrict__ apart, unsigned int* __restrict__ ticket) {
  __shared__ float sA[128][NM2];
  __shared__ float sB[128][NM2];
  const int c = blockIdx.x;
  const int k = threadIdx.x;

  if (c < 6) {
    const int i = c*128 + k;
    const float p0 = x[3*i], p1 = x[3*i+1], p2 = x[3*i+2];
    norms[i] = sqrtf(p0*p0 + p1*p1 + p2*p2);
  }
  if (c == 6) {
    apart[k] = 0.f; apart[CCH + k] = 0.f; apart[2*CCH + k] = 0.f;
    if (k == 0) *ticket = 0u;
  }

  {
    const float A0 = Wa1[3*k], A1 = Wa1[3*k+1], A2c = Wa1[3*k+2], A3 = ba1[k];
    const float B0 = Wb1[3*k], B1 = Wb1[3*k+1], B2c = Wb1[3*k+2], B3 = bb1[k];
    const float g0 = A3*B3;              // 1
    const float g1 = A2c*B3 + A3*B2c;    // v
    const float g2 = A2c*B2c;            // v^2
    const float g3 = A1*B3 + A3*B1;      // u
    const float g4 = A1*B2c + A2c*B1;    // u v
    const float g5 = A1*B1;              // u^2
    const float g6 = A0*B3 + A3*B0;      // d
    const float g7 = A0*B2c + A2c*B0;    // d v
    const float g8 = A0*B1 + A1*B0;      // d u
    const float g9 = A0*B0;              // d^2
    const float wa = Wa2[c*CCH + k];
    const float wb = Wb2[c*CCH + k];
    sA[k][0] = wa*g0; sB[k][0] = wb*g0;
    sA[k][1] = wa*g1; sB[k][1] = wb*g1;
    sA[k][2] = wa*g2; sB[k][2] = wb*g2;
    sA[k][3] = wa*g3; sB[k][3] = wb*g3;
    sA[k][4] = wa*g4; sB[k][4] = wb*g4;
    sA[k][5] = wa*g5; sB[k][5] = wb*g5;
    sA[k][6] = wa*g6; sB[k][6] = wb*g6;
    sA[k][7] = wa*g7; sB[k][7] = wb*g7;
    sA[k][8] = wa*g8; sB[k][8] = wb*g8;
    sA[k][9] = wa*g9; sB[k][9] = wb*g9;
  }
  __syncthreads();

  for (int s = 64; s >= 1; s >>= 1) {
    if (k < s) {
      for (int t = 0; t < NM2; ++t) {
        sA[k][t] += sA[k+s][t];
        sB[k][t] += sB[k+s][t];
      }
    }
    __syncthreads();
  }
  if (k == 0) {
    sA[0][0] += ba2[c];
    sB[0][0] += bb2[c];
  }
  __syncthreads();

  if (k < 35) {
    int rem = k, a = 0;
    while (rem >= (5 - a)*(6 - a)/2) { rem -= (5 - a)*(6 - a)/2; ++a; }
    int b = 0;
    while (rem >= 5 - a - b) { rem -= 5 - a - b; ++b; }
    const int cc = rem;
    float s = 0.f;
    const int deg = a + b + cc;
    for (int a1 = 0; a1 <= a && a1 <= 2; ++a1)
      for (int b1 = 0; b1 <= b && b1 <= 2; ++b1)
        for (int c1 = 0; c1 <= cc && c1 <= 2; ++c1) {
          const int d1 = a1 + b1 + c1;
          if (d1 <= 2 && (deg - d1) <= 2)
            s += sA[0][t2i(a1, b1, c1)]
               * sB[0][t2i(a - a1, b - b1, cc - c1)];
        }
    C2m[c*NM4 + k] = s;
  }
  if (k == 35) C2m[c*NM4 + 35] = 0.f;
}

// ---------------------------------------------------------------------------
// k_pre2 (128 blocks x 64 thr): A3mT/B3mT = layer-3 fold, transposed (36x128).
// ---------------------------------------------------------------------------
__global__ void k_pre2(const float* __restrict__ Wa3, const float* __restrict__ ba3,
                       const float* __restrict__ Wb3, const float* __restrict__ bb3,
                       const float* __restrict__ C2m,
                       float* __restrict__ A3mT, float* __restrict__ B3mT) {
  const int c = blockIdx.x;
  const int j = threadIdx.x;
  if (j >= NM4) return;
  float sa = 0.f, sb = 0.f;
  if (j < 35) {
    for (int k = 0; k < CCH; ++k) {
      const float v = C2m[k*NM4 + j];
      sa += Wa3[c*CCH + k] * v;
      sb += Wb3[c*CCH + k] * v;
    }
    if (j == 0) { sa += ba3[c]; sb += bb3[c]; }
  }
  A3mT[j*CCH + c] = sa;
  B3mT[j*CCH + c] = sb;
}

// 12 MFMAs of one tile; first of each chain consumes the hoisted zero Z
// (no per-tile acc re-zero — saves 32 v_mov/tile).
#define MFMA12Z(AA0, AA1, AA2)                                                 \
  do {                                                                         \
    accA = __builtin_amdgcn_mfma_f32_32x32x16_bf16((AA2).h, ba0.h, Z,    0,0,0);\
    accA = __builtin_amdgcn_mfma_f32_32x32x16_bf16((AA1).h, ba1.h, accA, 0,0,0);\
    accA = __builtin_amdgcn_mfma_f32_32x32x16_bf16((AA0).h, ba2.h, accA, 0,0,0);\
    accA = __builtin_amdgcn_mfma_f32_32x32x16_bf16((AA1).h, ba0.h, accA, 0,0,0);\
    accA = __builtin_amdgcn_mfma_f32_32x32x16_bf16((AA0).h, ba1.h, accA, 0,0,0);\
    accA = __builtin_amdgcn_mfma_f32_32x32x16_bf16((AA0).h, ba0.h, accA, 0,0,0);\
    accB = __builtin_amdgcn_mfma_f32_32x32x16_bf16((AA2).h, bb0.h, Z,    0,0,0);\
    accB = __builtin_amdgcn_mfma_f32_32x32x16_bf16((AA1).h, bb1.h, accB, 0,0,0);\
    accB = __builtin_amdgcn_mfma_f32_32x32x16_bf16((AA0).h, bb2.h, accB, 0,0,0);\
    accB = __builtin_amdgcn_mfma_f32_32x32x16_bf16((AA1).h, bb0.h, accB, 0,0,0);\
    accB = __builtin_amdgcn_mfma_f32_32x32x16_bf16((AA0).h, bb1.h, accB, 0,0,0);\
    accB = __builtin_amdgcn_mfma_f32_32x32x16_bf16((AA0).h, bb0.h, accB, 0,0,0);\
  } while (0)

// Max tree over 16 floats (v_max3-friendly).
#define MAXTREE(F, OUT)                                                        \
  const float _x0 = fmaxf(fmaxf(F[0], F[1]), F[2]);                            \
  const float _x1 = fmaxf(fmaxf(F[3], F[4]), F[5]);                            \
  const float _x2 = fmaxf(fmaxf(F[6], F[7]), F[8]);                            \
  const float _x3 = fmaxf(fmaxf(F[9], F[10]), F[11]);                          \
  const float _x4 = fmaxf(fmaxf(F[12], F[13]), F[14]);                         \
  const float OUT = fmaxf(fmaxf(fmaxf(_x0, _x1), _x2),                         \
                          fmaxf(fmaxf(_x3, _x4), F[15]));

// PV over one tile; E_EXPR(r) gives the exp2 argument for slot r.
#define PVBLK(TB, E_EXPR)                                                      \
  _Pragma("unroll")                                                            \
  for (int rg = 0; rg < 4; ++rg) {                                             \
    _Pragma("unroll")                                                          \
    for (int q = 0; q < 4; ++q) {                                              \
      const int r = rg*4 + q;                                                  \
      const float e = fast_exp2(E_EXPR);                                       \
      const float4 xv = xt[(TB) + rg*8 + hl*4 + q];                            \
      srun += e;                                                               \
      a0r = fmaf(e, xv.x, a0r);                                                \
      a1r = fmaf(e, xv.y, a1r);                                                \
      a2r = fmaf(e, xv.z, a2r);                                                \
    }                                                                          \
  }

// ---------------------------------------------------------------------------
// k_main (v14 = final = v9/v12, session best: k_main 46.7 us): grid (768, 4),
// 256 thr = 4 waves; block owns one m, wave owns one 32-col c-tile.
// Converged structure after 13 rounds:
//  - bf16x3 split-MFMA logits (6 products >= 2^-18, fp32-level accuracy),
//    32x32x16 MFMA, verified A/C-D lane layouts;
//  - block-shared A-fragments built once into LDS (R5, -7 us);
//  - 1-deep MFMA software pipeline: next tile's ds_reads + 12 MFMAs issued
//    under this tile's softmax+PV (R7, -2 us);
//  - hoisted-Z acc init, fma drain fold, branch-free single-path online
//    rescale (R9, -1 us).
// Refuted levers (do NOT revisit): launch_bounds > 4 waves/EU (R3/R11:
// pipeline live-set > 84 VGPR -> wholesale scratch spill); 512-thr blocks
// (R6: anomalous scratch + no occupancy gain); HBM-staged fragment
// precompute (R1/R10: poisoned-ws round-trip costs more than the fold);
// divergent softmax paths (R8: duplicated PV -> spill); PV chain-split
// (R13: trans-serialized, +1.5 us). Inner loop is exp2-issue-dominated
// (16 quarter-rate v_exp_f32/tile, algorithmically irreducible).
// A layout: row=lane&31, k=(lane>>5)*8+e, word pairs lo/hi. C/D (verified):
// col=lane&31, row=(reg&3)+8*(reg>>2)+4*(lane>>5).
// ---------------------------------------------------------------------------
__global__ __launch_bounds__(256, 4) void k_main(
    const float* __restrict__ x, const float* __restrict__ norms,
    const float* __restrict__ A3mT, const float* __restrict__ B3mT,
    float* __restrict__ Mp, float* __restrict__ Sp,
    float* __restrict__ A0p, float* __restrict__ A1p, float* __restrict__ A2p) {
  __shared__ __align__(16) float4 xt[CTILE];       // (x0,x1,x2,|x_n|), 3 KB
  __shared__ __align__(16) uint4 af[NT][3][64];    // A-frags: tile x split x lane, 18 KB
  const int tid = threadIdx.x;
  const int wid = tid >> 6;          // c-tile index 0..3
  const int lane = tid & 63;
  const int hl = lane >> 5;          // k-slice half
  const int ln = lane & 31;          // A row / B,C col
  const int m = blockIdx.x;
  const int chunk = blockIdx.y;
  const int c = wid*32 + ln;         // this lane's channel column

  // Stage this chunk's 192 n's (x, |x|) into LDS.
  for (int p = tid; p < CTILE; p += 256) {
    const int n = chunk*CTILE + p;
    xt[p] = make_float4(x[3*n], x[3*n+1], x[3*n+2], norms[n]);
  }

  const float u = norms[m];
  const float xm0 = x[3*m], xm1 = x[3*m+1], xm2 = x[3*m+2];
  const float uu = u*u;
  const float u1 = u, u2 = uu, u3 = uu*u, u4 = uu*uu;

  // ---- B-fragments: compile-time u-fold + split3 + MFMA-pack -------------
  Frag ba0, ba1, ba2, bb0, bb1, bb2;
  if (hl == 0) {
    fold_word<0,1>(A3mT, B3mT, c, u1,u2,u3,u4, ba0.u[0],ba1.u[0],ba2.u[0], bb0.u[0],bb1.u[0],bb2.u[0]);
    fold_word<2,3>(A3mT, B3mT, c, u1,u2,u3,u4, ba0.u[1],ba1.u[1],ba2.u[1], bb0.u[1],bb1.u[1],bb2.u[1]);
    fold_word<4,5>(A3mT, B3mT, c, u1,u2,u3,u4, ba0.u[2],ba1.u[2],ba2.u[2], bb0.u[2],bb1.u[2],bb2.u[2]);
    fold_word<6,7>(A3mT, B3mT, c, u1,u2,u3,u4, ba0.u[3],ba1.u[3],ba2.u[3], bb0.u[3],bb1.u[3],bb2.u[3]);
  } else {
    fold_word<8,9>  (A3mT, B3mT, c, u1,u2,u3,u4, ba0.u[0],ba1.u[0],ba2.u[0], bb0.u[0],bb1.u[0],bb2.u[0]);
    fold_word<10,11>(A3mT, B3mT, c, u1,u2,u3,u4, ba0.u[1],ba1.u[1],ba2.u[1], bb0.u[1],bb1.u[1],bb2.u[1]);
    fold_word<12,13>(A3mT, B3mT, c, u1,u2,u3,u4, ba0.u[2],ba1.u[2],ba2.u[2], bb0.u[2],bb1.u[2],bb2.u[2]);
    fold_word<14,15>(A3mT, B3mT, c, u1,u2,u3,u4, ba0.u[3],ba1.u[3],ba2.u[3], bb0.u[3],bb1.u[3],bb2.u[3]);
  }

  __syncthreads();   // xt staged

  // ---- Build phase: this wave builds A-frags for tiles wid, wid+4 --------
  for (int t = wid; t < NT; t += 4) {
    const float4 xn = xt[t*32 + ln];
    const float v = xn.w;
    const float dot = xm0*xn.x + xm1*xn.y + xm2*xn.z;
    const float d2 = uu + v*v - 2.f*dot;
    const float d = (d2 > 0.f) ? sqrtf(d2) : 0.f;   // grad-safe cdist semantics
    const float v2 = v*v, v3 = v2*v, v4 = v2*v2;
    const float dd = d*d, d3 = dd*d, d4 = dd*dd;
    float mono[8];
    if (hl == 0) {
      mono[0] = 1.f;   mono[1] = v;     mono[2] = v2;    mono[3] = v3;
      mono[4] = v4;    mono[5] = d;     mono[6] = d*v;   mono[7] = d*v2;
    } else {
      mono[0] = d*v3;  mono[1] = dd;    mono[2] = dd*v;  mono[3] = dd*v2;
      mono[4] = d3;    mono[5] = d3*v;  mono[6] = d4;    mono[7] = 0.f;
    }
    Frag A0f, A1f, A2f;
    #pragma unroll
    for (int p = 0; p < 4; ++p) {
      unsigned int l0, l1, l2, g0, g1, g2;
      split3(mono[2*p],   l0, l1, l2);
      split3(mono[2*p+1], g0, g1, g2);
      A0f.u[p] = l0 | (g0 << 16);
      A1f.u[p] = l1 | (g1 << 16);
      A2f.u[p] = l2 | (g2 << 16);
    }
    af[t][0][lane] = *(const uint4*)A0f.u;
    af[t][1][lane] = *(const uint4*)A1f.u;
    af[t][2][lane] = *(const uint4*)A2f.u;
  }

  __syncthreads();   // A-frags built

  float mrun, srun = 0.f, a0r = 0.f, a1r = 0.f, a2r = 0.f;

  f32x16 Z;
  #pragma unroll
  for (int r = 0; r < 16; ++r) Z[r] = 0.f;

  // ---- Pipeline prologue: tile 0's MFMAs in flight before the loop ----
  Frag A0f, A1f, A2f;
  *(uint4*)A0f.u = af[0][0][lane];
  *(uint4*)A1f.u = af[0][1][lane];
  *(uint4*)A2f.u = af[0][2][lane];
  f32x16 accA, accB;
  MFMA12Z(A0f, A1f, A2f);

  // ---- Tile 0 (peeled: no prior max) ----
  {
    *(uint4*)A0f.u = af[1][0][lane];
    *(uint4*)A1f.u = af[1][1][lane];
    *(uint4*)A2f.u = af[1][2][lane];
    float f[16];
    #pragma unroll
    for (int r = 0; r < 16; ++r) f[r] = accA[r]*accB[r];   // logits * log2e
    MFMA12Z(A0f, A1f, A2f);                                 // tile 1 in flight
    MAXTREE(f, hx0);
    mrun = hx0;
    PVBLK(0, f[r] - hx0);
  }

  for (int tile = 1; tile < NT; ++tile) {
    // Prefetch next tile's A-frags (issue only; consumed after f extract).
    if (tile + 1 < NT) {
      *(uint4*)A0f.u = af[tile+1][0][lane];
      *(uint4*)A1f.u = af[tile+1][1][lane];
      *(uint4*)A2f.u = af[tile+1][2][lane];
    }

    // Drain this tile's accumulators (waits on the in-flight MFMA chain);
    // -mrun folded into the drain fma.
    float f[16];
    #pragma unroll
    for (int r = 0; r < 16; ++r) f[r] = fmaf(accA[r], accB[r], -mrun);

    // Issue next tile's MFMAs now — they execute under this tile's softmax.
    if (tile + 1 < NT) MFMA12Z(A0f, A1f, A2f);

    // Branch-free online update: fxp = max growth (0 when max unchanged —
    // then sc = exp2(0) = 1 and the rescale is a no-op, exactly as R7).
    MAXTREE(f, fx);
    const float fxp = fmaxf(fx, 0.f);
    const float sc = fast_exp2(-fxp);
    mrun += fxp;
    srun *= sc; a0r *= sc; a1r *= sc; a2r *= sc;
    PVBLK(tile*32, f[r] - fxp);
  }

  // Merge the two lane-halves' online states (each covered half the rows).
  {
    const float om = __shfl_xor(mrun, 32);
    const float os = __shfl_xor(srun, 32);
    const float o0 = __shfl_xor(a0r, 32);
    const float o1 = __shfl_xor(a1r, 32);
    const float o2 = __shfl_xor(a2r, 32);
    const float M  = fmaxf(mrun, om);
    const float e1 = fast_exp2(mrun - M);
    const float e2 = fast_exp2(om - M);
    if (hl == 0) {
      const int idx = chunk*PAIR + m*CCH + c;
      Mp[idx]  = M;
      Sp[idx]  = fmaf(srun, e1, os*e2);
      A0p[idx] = fmaf(a0r, e1, o0*e2);
      A1p[idx] = fmaf(a1r, e1, o1*e2);
      A2p[idx] = fmaf(a2r, e1, o2*e2);
    }
  }
}

// ---------------------------------------------------------------------------
// k_fin (96 blocks x 256): merge NCHUNK=4 partials per (m,c), normalize,
// LDS-reduce 8 m-rows, atomics into apart; ticketed Wf contraction + out.
// ---------------------------------------------------------------------------
__global__ __launch_bounds__(256) void k_fin(
    const float* __restrict__ x,
    const float* __restrict__ Mp, const float* __restrict__ Sp,
    const float* __restrict__ A0p, const float* __restrict__ A1p,
    const float* __restrict__ A2p,
    const float* __restrict__ Wf,
    float* __restrict__ apart, unsigned int* __restrict__ ticket,
    float* __restrict__ out) {
  __shared__ float red2[2][3][CCH];
  __shared__ float red[CCH][6];
  __shared__ bool last;
  const int tid = threadIdx.x;
  const int ml = tid >> 7;
  const int c = tid & 127;

  float s0 = 0.f, s1 = 0.f, s2 = 0.f;
  #pragma unroll
  for (int j = 0; j < 4; ++j) {
    const int m = blockIdx.x*8 + ml*4 + j;
    const int gid = m*CCH + c;
    float mm[NCHUNK];
    #pragma unroll
    for (int p = 0; p < NCHUNK; ++p) mm[p] = Mp[p*PAIR + gid];
    float M = mm[0];
    #pragma unroll
    for (int p = 1; p < NCHUNK; ++p) M = fmaxf(M, mm[p]);
    float W = 0.f, g0 = 0.f, g1 = 0.f, g2 = 0.f;
    #pragma unroll
    for (int p = 0; p < NCHUNK; ++p) {
      const float ep = fast_exp2(mm[p] - M);
      W  = fmaf(Sp[p*PAIR+gid],  ep, W);
      g0 = fmaf(A0p[p*PAIR+gid], ep, g0);
      g1 = fmaf(A1p[p*PAIR+gid], ep, g1);
      g2 = fmaf(A2p[p*PAIR+gid], ep, g2);
    }
    const float inv = 1.f / W;
    s0 = fmaf(g0, inv, s0);
    s1 = fmaf(g1, inv, s1);
    s2 = fmaf(g2, inv, s2);
  }
  red2[ml][0][c] = s0; red2[ml][1][c] = s1; red2[ml][2][c] = s2;
  __syncthreads();
  for (int p = tid; p < NACC; p += 256) {
    const int i = p >> 7, cc = p & 127;
    atomicAdd(&apart[p], red2[0][i][cc] + red2[1][i][cc]);
  }
  __threadfence();
  __syncthreads();
  if (tid == 0) {
    const unsigned int old = atomicAdd(ticket, 1u);
    last = (old == FINB - 1);
  }
  __syncthreads();
  if (!last) return;
  __threadfence();

  if (tid < CCH) {
    const int cc = tid;
    const float a0 = __hip_atomic_load(&apart[cc],          __ATOMIC_RELAXED, __HIP_MEMORY_SCOPE_AGENT);
    const float a1 = __hip_atomic_load(&apart[CCH + cc],    __ATOMIC_RELAXED, __HIP_MEMORY_SCOPE_AGENT);
    const float a2 = __hip_atomic_load(&apart[2*CCH + cc],  __ATOMIC_RELAXED, __HIP_MEMORY_SCOPE_AGENT);
    const float w0 = Wf[cc], w1 = Wf[CCH + cc];
    red[cc][0] = w0*a0; red[cc][1] = w0*a1; red[cc][2] = w0*a2;
    red[cc][3] = w1*a0; red[cc][4] = w1*a1; red[cc][5] = w1*a2;
  }
  __syncthreads();
  if (tid < 6) {
    float s = 0.f;
    for (int k = 0; k < CCH; ++k) s += red[k][tid];
    out[3 + tid] = s;
  }
  if (tid < 3) out[tid] = x[tid];
}

// ---------------------------------------------------------------------------
extern "C" void kernel_launch(void* const* d_in, const int* in_sizes, int n_in,
                              void* d_out, int out_size, void* d_ws, size_t ws_size,
                              hipStream_t stream) {
  const float* x   = (const float*)d_in[0];
  const float* Wa1 = (const float*)d_in[1];
  const float* ba1 = (const float*)d_in[2];
  const float* Wb1 = (const float*)d_in[3];
  const float* bb1 = (const float*)d_in[4];
  const float* Wa2 = (const float*)d_in[5];
  const float* ba2 = (const float*)d_in[6];
  const float* Wb2 = (const float*)d_in[7];
  const float* bb2 = (const float*)d_in[8];
  const float* Wa3 = (const float*)d_in[9];
  const float* ba3 = (const float*)d_in[10];
  const float* Wb3 = (const float*)d_in[11];
  const float* bb3 = (const float*)d_in[12];
  const float* Wf  = (const float*)d_in[13];
  float* out = (float*)d_out;

  float* ws     = (float*)d_ws;
  float* norms  = ws;                      // 768
  float* C2m    = norms + NPTS;            // 128*36
  float* A3mT   = C2m   + CCH*NM4;         // 36*128
  float* B3mT   = A3mT  + NM4*CCH;         // 36*128
  float* Mp     = B3mT  + NM4*CCH;         // 4*98304
  float* Sp     = Mp    + NCHUNK*PAIR;
  float* A0p    = Sp    + NCHUNK*PAIR;
  float* A1p    = A0p   + NCHUNK*PAIR;
  float* A2p    = A1p   + NCHUNK*PAIR;
  float* apart  = A2p   + NCHUNK*PAIR;     // 384
  unsigned int* ticket = (unsigned int*)(apart + NACC);

  hipLaunchKernelGGL(k_fold12, dim3(CCH), dim3(128), 0, stream,
                     x, Wa1, ba1, Wb1, bb1, Wa2, ba2, Wb2, bb2,
                     norms, C2m, apart, ticket);
  hipLaunchKernelGGL(k_pre2, dim3(CCH), dim3(64), 0, stream,
                     Wa3, ba3, Wb3, bb3, C2m, A3mT, B3mT);
  hipLaunchKernelGGL(k_main, dim3(NPTS, NCHUNK), dim3(256), 0, stream,
                     x, norms, A3mT, B3mT, Mp, Sp, A0p, A1p, A2p);
  hipLaunchKernelGGL(k_fin, dim3(FINB), dim3(256), 0, stream,
                     x, Mp, Sp, A0p, A1p, A2p, Wf, apart, ticket, out);
}